// Round 15
// baseline (271.248 us; speedup 1.0000x reference)
//
#include <hip/hip_runtime.h>
#include <hip/hip_bf16.h>

#define DI __device__ __forceinline__

typedef __attribute__((ext_vector_type(8))) short bh8;   // 8 bf16 (4 VGPR) MFMA frag
typedef __attribute__((ext_vector_type(8))) unsigned short us8;
typedef __attribute__((ext_vector_type(4))) float f4ev;  // MFMA f32 accumulator

static constexpr int Bn = 4;
static constexpr int Nn = 4096;
static constexpr int Cn = 768;
static constexpr int Hn = 12;
static constexpr int Dn = 64;    // head dim
static constexpr int Ln = 64;    // landmarks
static constexpr int TOKS = Bn * Nn;   // 16384
static constexpr int BHn = Bn * Hn;    // 48

// ---- workspace layout (bytes); stays within the proven ~110 MB footprint ----
static constexpr size_t SZ_XB  = (size_t)TOKS * Cn * 2;       // 25165824
static constexpr size_t SZ_QKV = (size_t)BHn * Nn * Dn * 2;   // 25165824
static constexpr size_t OFF_XB   = 0;                         // xb; later ocp; later oh
static constexpr size_t OFF_QB   = OFF_XB + SZ_XB;            // land partials live here pre-gemm_qkv
static constexpr size_t OFF_KB   = OFF_QB + SZ_QKV;
static constexpr size_t OFF_VB   = OFF_KB + SZ_QKV;
static constexpr size_t OFF_WQB  = OFF_VB + SZ_QKV;
static constexpr size_t OFF_WPB  = OFF_WQB + (size_t)3 * Cn * Cn * 2;
static constexpr size_t OFF_XM   = OFF_WPB + (size_t)Cn * Cn * 2;
static constexpr size_t OFF_QL   = OFF_XM + (size_t)Bn * Ln * Cn * 4;
static constexpr size_t OFF_KL   = OFF_QL + (size_t)Bn * Ln * Cn * 4;
static constexpr size_t OFF_VINV = OFF_KL + (size_t)Bn * Ln * Cn * 4;
static constexpr size_t OFF_CP   = OFF_VINV + (size_t)BHn * 64 * 64 * 4;  // stats: 48*32*64*2 f32
static constexpr size_t OFF_W2   = OFF_CP + (size_t)BHn * 32 * 64 * 2 * 4;

DI unsigned short f2bf(float f) {
  __hip_bfloat16 h = __float2bfloat16(f);
  return *reinterpret_cast<unsigned short*>(&h);
}
DI float bf2f(unsigned short u) {
  union { unsigned int i; float f; } c; c.i = ((unsigned)u) << 16; return c.f;
}

DI void gload_lds16(const void* g, void* l) {
  __builtin_amdgcn_global_load_lds((const __attribute__((address_space(1))) void*)g,
                                   (__attribute__((address_space(3))) void*)l, 16, 0, 0);
}

__global__ void cast_k(const float* __restrict__ s, unsigned short* __restrict__ d, int n4) {
  int i = blockIdx.x * blockDim.x + threadIdx.x;
  int st = gridDim.x * blockDim.x;
  const float4* s4 = (const float4*)s;
  ushort4* d4 = (ushort4*)d;
  for (; i < n4; i += st) {
    float4 v = s4[i];
    ushort4 o; o.x = f2bf(v.x); o.y = f2bf(v.y); o.z = f2bf(v.z); o.w = f2bf(v.w);
    d4[i] = o;
  }
}

// ---------- fused: cast x -> bf16 AND exact f32 segment-mean -> xm ----------
__global__ void castmean_k(const float* __restrict__ x, unsigned short* __restrict__ xb,
                           float* __restrict__ xm) {
  int bl = blockIdx.x, cz = blockIdx.y;
  int c = cz * 384 + threadIdx.x * 2;
  const float* xp = x + (size_t)bl * 64 * Cn + c;
  unsigned short* xbp = xb + (size_t)bl * 64 * Cn + c;
  float s0 = 0.f, s1 = 0.f;
  #pragma unroll 8
  for (int r = 0; r < 64; ++r) {
    float2 v = *(const float2*)(xp + (size_t)r * Cn);
    ushort2 o; o.x = f2bf(v.x); o.y = f2bf(v.y);
    *(ushort2*)(xbp + (size_t)r * Cn) = o;
    s0 += v.x; s1 += v.y;
  }
  xm[(size_t)bl * Cn + c]     = s0 * 0.015625f;
  xm[(size_t)bl * Cn + c + 1] = s1 * 0.015625f;
}

// ---------- landmark projection, K-split x12, register-blocked 4x4 ----------
__launch_bounds__(256)
__global__ void landgemm_k(const float* __restrict__ xm, const float* __restrict__ wqkv,
                           float* __restrict__ part) {
  __shared__ float XT[64][65];
  __shared__ float WT[64][65];
  int b = blockIdx.x, ct = blockIdx.y, kc = blockIdx.z;
  int t = threadIdx.x;
  int tr = t >> 4, tc = t & 15;
  int r0 = tr * 4, j0 = tc * 4;
  const float* xb_ = xm + (size_t)b * Ln * Cn + kc * 64;
  const float* wb_ = wqkv + (size_t)ct * 64 * Cn + kc * 64;
  #pragma unroll
  for (int i = t; i < 1024; i += 256) {
    int r = i >> 4, c4 = (i & 15) * 4;
    float4 xv = *(const float4*)(xb_ + (size_t)r * Cn + c4);
    XT[c4 + 0][r] = xv.x; XT[c4 + 1][r] = xv.y; XT[c4 + 2][r] = xv.z; XT[c4 + 3][r] = xv.w;
    float4 wv = *(const float4*)(wb_ + (size_t)r * Cn + c4);
    WT[c4 + 0][r] = wv.x; WT[c4 + 1][r] = wv.y; WT[c4 + 2][r] = wv.z; WT[c4 + 3][r] = wv.w;
  }
  __syncthreads();
  float acc[4][4];
  #pragma unroll
  for (int i = 0; i < 4; ++i)
    #pragma unroll
    for (int j = 0; j < 4; ++j) acc[i][j] = 0.f;
  for (int cc = 0; cc < 64; ++cc) {
    float4 a4 = *(const float4*)&XT[cc][r0];
    float4 b4 = *(const float4*)&WT[cc][j0];
    acc[0][0] += a4.x * b4.x; acc[0][1] += a4.x * b4.y; acc[0][2] += a4.x * b4.z; acc[0][3] += a4.x * b4.w;
    acc[1][0] += a4.y * b4.x; acc[1][1] += a4.y * b4.y; acc[1][2] += a4.y * b4.z; acc[1][3] += a4.y * b4.w;
    acc[2][0] += a4.z * b4.x; acc[2][1] += a4.z * b4.y; acc[2][2] += a4.z * b4.z; acc[2][3] += a4.z * b4.w;
    acc[3][0] += a4.w * b4.x; acc[3][1] += a4.w * b4.y; acc[3][2] += a4.w * b4.z; acc[3][3] += a4.w * b4.w;
  }
  float* op = part + ((size_t)kc * 256 + b * Ln) * 1536 + (size_t)ct * 64;
  #pragma unroll
  for (int i = 0; i < 4; ++i)
    *(float4*)(op + (size_t)(r0 + i) * 1536 + j0) = make_float4(acc[i][0], acc[i][1], acc[i][2], acc[i][3]);
}

// ---------- sum 12 K-split partials -> ql (x0.125), kl ----------
__global__ void landred_k(const float* __restrict__ part, float* __restrict__ ql,
                          float* __restrict__ kl) {
  int i4 = blockIdx.x * 256 + threadIdx.x;
  const float4* p4 = (const float4*)part;
  float4 s = p4[i4];
  #pragma unroll
  for (int kc = 1; kc < 12; ++kc) {
    float4 v = p4[(size_t)kc * 98304 + i4];
    s.x += v.x; s.y += v.y; s.z += v.z; s.w += v.w;
  }
  int row = i4 / 384, c = (i4 % 384) * 4;
  if (c < 768) {
    s.x *= 0.125f; s.y *= 0.125f; s.z *= 0.125f; s.w *= 0.125f;
    *(float4*)(ql + (size_t)row * Cn + c) = s;
  } else {
    *(float4*)(kl + (size_t)row * Cn + (c - 768)) = s;
  }
}

// ---------- kernel_2 softmax + 6-iter Newton-Schulz inverse ----------
__launch_bounds__(256)
__global__ void k2inv_k(const float* __restrict__ ql, const float* __restrict__ kl,
                        float* __restrict__ vinv) {
  __shared__ float B0[64][68], B1[64][68], B2[64][68], B3[64][68],
                   B4[64][68], B5[64][68], B6[64][68], B7[64][68];
  __shared__ float dinv_s;
  float (*Qt)[68] = B0, (*Kt)[68] = B1;
  float (*KV)[68] = B0, (*KVt)[68] = B1;
  float (*K2)[68] = B2, (*K2t)[68] = B3;
  float (*Vv)[68] = B4, (*Vt)[68] = B5;
  float (*T1)[68] = B6, (*Uu)[68] = B7;

  int bh = blockIdx.x, b = bh / Hn, h = bh % Hn;
  int t = threadIdx.x;
  int tr = t >> 4, tc = t & 15;
  int r0 = tr * 4, j0 = tc * 4;

  {
    const float* qbase = ql + (size_t)(b * Ln) * Cn + h * Dn;
    const float* kbase = kl + (size_t)(b * Ln) * Cn + h * Dn;
    #pragma unroll
    for (int it = 0; it < 4; ++it) {
      int idx = it * 256 + t;
      int l = idx >> 4, d0 = (idx & 15) * 4;
      float4 qv = *(const float4*)(qbase + (size_t)l * Cn + d0);
      float4 kv = *(const float4*)(kbase + (size_t)l * Cn + d0);
      Qt[d0 + 0][l] = qv.x; Qt[d0 + 1][l] = qv.y; Qt[d0 + 2][l] = qv.z; Qt[d0 + 3][l] = qv.w;
      Kt[d0 + 0][l] = kv.x; Kt[d0 + 1][l] = kv.y; Kt[d0 + 2][l] = kv.z; Kt[d0 + 3][l] = kv.w;
    }
  }
  __syncthreads();

  float acc[4][4];
  #define MM64(LT, RR)                                                     \
    {                                                                      \
      _Pragma("unroll")                                                    \
      for (int i_ = 0; i_ < 4; ++i_)                                       \
        _Pragma("unroll")                                                  \
        for (int j_ = 0; j_ < 4; ++j_) acc[i_][j_] = 0.f;                  \
      for (int c_ = 0; c_ < 64; c_ += 4) {                                 \
        _Pragma("unroll")                                                  \
        for (int cc_ = 0; cc_ < 4; ++cc_) {                                \
          float4 a4 = *(const float4*)&LT[c_ + cc_][r0];                   \
          float4 b4 = *(const float4*)&RR[c_ + cc_][j0];                   \
          acc[0][0] += a4.x * b4.x; acc[0][1] += a4.x * b4.y;              \
          acc[0][2] += a4.x * b4.z; acc[0][3] += a4.x * b4.w;              \
          acc[1][0] += a4.y * b4.x; acc[1][1] += a4.y * b4.y;              \
          acc[1][2] += a4.y * b4.z; acc[1][3] += a4.y * b4.w;              \
          acc[2][0] += a4.z * b4.x; acc[2][1] += a4.z * b4.y;              \
          acc[2][2] += a4.z * b4.z; acc[2][3] += a4.z * b4.w;              \
          acc[3][0] += a4.w * b4.x; acc[3][1] += a4.w * b4.y;              \
          acc[3][2] += a4.w * b4.z; acc[3][3] += a4.w * b4.w;              \
        }                                                                  \
      }                                                                    \
    }

  MM64(Qt, Kt);
  #pragma unroll
  for (int i = 0; i < 4; ++i)
    *(float4*)&K2[r0 + i][j0] = make_float4(acc[i][0], acc[i][1], acc[i][2], acc[i][3]);
  __syncthreads();

  if (t < 64) {
    float m = -1e30f;
    #pragma unroll
    for (int c4 = 0; c4 < 16; ++c4) {
      float4 v = *(const float4*)&K2[t][c4 * 4];
      m = fmaxf(m, fmaxf(fmaxf(v.x, v.y), fmaxf(v.z, v.w)));
    }
    float s = 0.f;
    #pragma unroll
    for (int c4 = 0; c4 < 16; ++c4) {
      float4 v = *(const float4*)&K2[t][c4 * 4];
      v.x = __expf(v.x - m); v.y = __expf(v.y - m);
      v.z = __expf(v.z - m); v.w = __expf(v.w - m);
      s += v.x + v.y + v.z + v.w;
      *(float4*)&K2[t][c4 * 4] = v;
    }
    float inv = 1.f / s;
    #pragma unroll
    for (int c4 = 0; c4 < 16; ++c4) {
      float4 v = *(const float4*)&K2[t][c4 * 4];
      v.x *= inv; v.y *= inv; v.z *= inv; v.w *= inv;
      *(float4*)&K2[t][c4 * 4] = v;
      K2t[c4 * 4 + 0][t] = v.x; K2t[c4 * 4 + 1][t] = v.y;
      K2t[c4 * 4 + 2][t] = v.z; K2t[c4 * 4 + 3][t] = v.w;
    }
  }
  __syncthreads();
  if (t < 64) {
    float cs = 0.f;
    #pragma unroll
    for (int c4 = 0; c4 < 16; ++c4) {
      float4 v = *(const float4*)&K2t[t][c4 * 4];
      cs += v.x + v.y + v.z + v.w;
    }
    #pragma unroll
    for (int off = 1; off < 64; off <<= 1) cs = fmaxf(cs, __shfl_xor(cs, off));
    if (t == 0) dinv_s = 1.f / cs;
  }
  __syncthreads();
  float dinv = dinv_s;
  #pragma unroll
  for (int jj = 0; jj < 4; ++jj) {
    float4 k4 = *(const float4*)&K2[j0 + jj][r0];
    k4.x *= dinv; k4.y *= dinv; k4.z *= dinv; k4.w *= dinv;
    *(float4*)&Vt[j0 + jj][r0] = k4;
    Vv[r0 + 0][j0 + jj] = k4.x; Vv[r0 + 1][j0 + jj] = k4.y;
    Vv[r0 + 2][j0 + jj] = k4.z; Vv[r0 + 3][j0 + jj] = k4.w;
  }
  __syncthreads();

  float nv[4][4];
  for (int itn = 0; itn < 6; ++itn) {
    MM64(K2t, Vv);
    #pragma unroll
    for (int i = 0; i < 4; ++i)
      *(float4*)&KV[r0 + i][j0] = make_float4(acc[i][0], acc[i][1], acc[i][2], acc[i][3]);
    #pragma unroll
    for (int jj = 0; jj < 4; ++jj)
      *(float4*)&KVt[j0 + jj][r0] = make_float4(acc[0][jj], acc[1][jj], acc[2][jj], acc[3][jj]);
    __syncthreads();
    MM64(KVt, KV);
    #pragma unroll
    for (int i = 0; i < 4; ++i) {
      float4 kv4 = *(const float4*)&KV[r0 + i][j0];
      *(float4*)&T1[r0 + i][j0] = make_float4(7.f * kv4.x - acc[i][0], 7.f * kv4.y - acc[i][1],
                                              7.f * kv4.z - acc[i][2], 7.f * kv4.w - acc[i][3]);
    }
    __syncthreads();
    MM64(KVt, T1);
    #pragma unroll
    for (int i = 0; i < 4; ++i) {
      float4 kv4 = *(const float4*)&KV[r0 + i][j0];
      *(float4*)&Uu[r0 + i][j0] = make_float4(15.f * kv4.x - acc[i][0], 15.f * kv4.y - acc[i][1],
                                              15.f * kv4.z - acc[i][2], 15.f * kv4.w - acc[i][3]);
    }
    __syncthreads();
    MM64(Vt, Uu);
    #pragma unroll
    for (int i = 0; i < 4; ++i) {
      float4 v4 = *(const float4*)&Vv[r0 + i][j0];
      nv[i][0] = 0.25f * (13.f * v4.x - acc[i][0]);
      nv[i][1] = 0.25f * (13.f * v4.y - acc[i][1]);
      nv[i][2] = 0.25f * (13.f * v4.z - acc[i][2]);
      nv[i][3] = 0.25f * (13.f * v4.w - acc[i][3]);
    }
    __syncthreads();
    #pragma unroll
    for (int i = 0; i < 4; ++i)
      *(float4*)&Vv[r0 + i][j0] = make_float4(nv[i][0], nv[i][1], nv[i][2], nv[i][3]);
    #pragma unroll
    for (int jj = 0; jj < 4; ++jj)
      *(float4*)&Vt[j0 + jj][r0] = make_float4(nv[0][jj], nv[1][jj], nv[2][jj], nv[3][jj]);
    __syncthreads();
  }
  float* op = vinv + (size_t)bh * 4096;
  #pragma unroll
  for (int i = 0; i < 4; ++i)
    *(float4*)(op + (size_t)(r0 + i) * 64 + j0) = make_float4(nv[i][0], nv[i][1], nv[i][2], nv[i][3]);
  #undef MM64
}

// ---------- big GEMM: BK=32 double-buffered (32 KB LDS -> ~5 blocks/CU) ----------
// Per K-tile: issue STAGE(next buf) FIRST, compute cur buf, ONE barrier.
// R7-proven zero-conflict BK=32 swizzle (scol/rcol lane-pure XOR).
__launch_bounds__(256)
__global__ void gemm_qkv_k(const __hip_bfloat16* __restrict__ A, const __hip_bfloat16* __restrict__ W,
                           __hip_bfloat16* __restrict__ qb, __hip_bfloat16* __restrict__ kb,
                           __hip_bfloat16* __restrict__ vb) {
  __shared__ unsigned short As[2][128][32], Bs[2][128][32];   // 32 KB
  int t = threadIdx.x, lane = t & 63, w = t >> 6;
  int wr = w >> 1, wc = w & 1;
  int m0 = blockIdx.x * 128, n0 = blockIdx.y * 128;
  int srow = lane >> 2;
  int scol = (((lane & 3) ^ ((lane >> 3) & 3))) * 8;        // swizzled source slot
  int rcol = (((lane >> 4) ^ ((lane >> 1) & 3))) * 8;       // swizzled read slot
  f4ev acc[4][4];
  f4ev zz = {0.f, 0.f, 0.f, 0.f};
  #pragma unroll
  for (int m = 0; m < 4; ++m)
    #pragma unroll
    for (int n = 0; n < 4; ++n) acc[m][n] = zz;
  const __hip_bfloat16* ga = A + (size_t)(m0 + w * 16 + srow) * Cn + scol;
  const __hip_bfloat16* gb = W + (size_t)(n0 + w * 16 + srow) * Cn + scol;

  // prologue: stage K-tile 0 into buffer 0
  gload_lds16(ga,                   &As[0][w * 16][0]);
  gload_lds16(ga + (size_t)64 * Cn, &As[0][64 + w * 16][0]);
  gload_lds16(gb,                   &Bs[0][w * 16][0]);
  gload_lds16(gb + (size_t)64 * Cn, &Bs[0][64 + w * 16][0]);
  __syncthreads();
  int cur = 0;
  for (int it = 0; it < 24; ++it) {
    if (it < 23) {
      int k0 = (it + 1) * 32;
      gload_lds16(ga + k0,                   &As[cur ^ 1][w * 16][0]);
      gload_lds16(ga + (size_t)64 * Cn + k0, &As[cur ^ 1][64 + w * 16][0]);
      gload_lds16(gb + k0,                   &Bs[cur ^ 1][w * 16][0]);
      gload_lds16(gb + (size_t)64 * Cn + k0, &Bs[cur ^ 1][64 + w * 16][0]);
    }
    bh8 af[4], bf_[4];
    #pragma unroll
    for (int m = 0; m < 4; ++m)
      af[m] = *(const bh8*)&As[cur][wr * 64 + m * 16 + (lane & 15)][rcol];
    #pragma unroll
    for (int n = 0; n < 4; ++n)
      bf_[n] = *(const bh8*)&Bs[cur][wc * 64 + n * 16 + (lane & 15)][rcol];
    #pragma unroll
    for (int m = 0; m < 4; ++m)
      #pragma unroll
      for (int n = 0; n < 4; ++n)
        acc[m][n] = __builtin_amdgcn_mfma_f32_16x16x32_bf16(af[m], bf_[n], acc[m][n], 0, 0, 0);
    __syncthreads();   // drains this iter's prefetch (vmcnt) + cur-buffer reads (lgkm)
    cur ^= 1;
  }
  int which = (n0 >= 1536) ? 2 : (n0 >= 768 ? 1 : 0);
  __hip_bfloat16* dst = which == 0 ? qb : (which == 1 ? kb : vb);
  float sc = which == 0 ? 0.125f : 1.f;
  #pragma unroll
  for (int m = 0; m < 4; ++m) {
    int rbase = m0 + wr * 64 + m * 16 + ((lane >> 4) << 2);
    #pragma unroll
    for (int n = 0; n < 4; ++n) {
      int c = n0 + wc * 64 + n * 16 + (lane & 15);
      int rem = c - which * 768;
      int h = rem >> 6, dd = rem & 63;
      #pragma unroll
      for (int jj = 0; jj < 4; ++jj) {
        int r = rbase + jj;
        int b = r >> 12, ntok = r & 4095;
        dst[(((size_t)(b * Hn + h) * Nn + ntok) << 6) + dd] = __float2bfloat16(acc[m][n][jj] * sc);
      }
    }
  }
}

// ---------- fused flash-style kernel_3 softmax + @v over 128-token chunks ----------
__launch_bounds__(256)
__global__ void k3vflash_k(const float* __restrict__ ql, const __hip_bfloat16* __restrict__ kb,
                           const __hip_bfloat16* __restrict__ vb,
                           float* __restrict__ ocp, float* __restrict__ stat) {
  __shared__ unsigned short Ks[128][72];   // K tile [token][d]; reused as Pl[64][136]
  __shared__ unsigned short VT[64][136];   // V^T tile [d][token]
  auto Pl = (unsigned short (*)[136]) & Ks[0][0];
  int ch = blockIdx.x, bh = blockIdx.y;
  int b = bh / Hn, h = bh % Hn;
  int t = threadIdx.x, lane = t & 63, w = t >> 6;

  {
    int row = t >> 1, half = (t & 1) * 32;
    const us8* krow = (const us8*)((const unsigned short*)kb + ((size_t)bh * Nn + (size_t)ch * 128 + row) * Dn + half);
    const us8* vrow = (const us8*)((const unsigned short*)vb + ((size_t)bh * Nn + (size_t)ch * 128 + row) * Dn + half);
    us8 kv0 = krow[0], kv1 = krow[1], kv2 = krow[2], kv3 = krow[3];
    us8 vv0 = vrow[0], vv1 = vrow[1], vv2 = vrow[2], vv3 = vrow[3];
    *(us8*)&Ks[row][half + 0]  = kv0;
    *(us8*)&Ks[row][half + 8]  = kv1;
    *(us8*)&Ks[row][half + 16] = kv2;
    *(us8*)&Ks[row][half + 24] = kv3;
    #pragma unroll
    for (int e = 0; e < 8; ++e) {
      VT[half + e][row]      = vv0[e];
      VT[half + 8 + e][row]  = vv1[e];
      VT[half + 16 + e][row] = vv2[e];
      VT[half + 24 + e][row] = vv3[e];
    }
  }
  bh8 aq[2];
  {
    const float* qrow = ql + ((size_t)(b * Ln + w * 16 + (lane & 15))) * Cn + h * Dn + (lane >> 4) * 8;
    #pragma unroll
    for (int ks = 0; ks < 2; ++ks) {
      float4 f0 = *(const float4*)(qrow + ks * 32);
      float4 f1 = *(const float4*)(qrow + ks * 32 + 4);
      bh8 v;
      v[0] = (short)f2bf(f0.x); v[1] = (short)f2bf(f0.y); v[2] = (short)f2bf(f0.z); v[3] = (short)f2bf(f0.w);
      v[4] = (short)f2bf(f1.x); v[5] = (short)f2bf(f1.y); v[6] = (short)f2bf(f1.z); v[7] = (short)f2bf(f1.w);
      aq[ks] = v;
    }
  }
  __syncthreads();
  f4ev sacc[8];
  f4ev zz = {0.f, 0.f, 0.f, 0.f};
  #pragma unroll
  for (int nt = 0; nt < 8; ++nt) sacc[nt] = zz;
  #pragma unroll
  for (int ks = 0; ks < 2; ++ks)
    #pragma unroll
    for (int nt = 0; nt < 8; ++nt) {
      bh8 bk = *(const bh8*)&Ks[nt * 16 + (lane & 15)][ks * 32 + (lane >> 4) * 8];
      sacc[nt] = __builtin_amdgcn_mfma_f32_16x16x32_bf16(aq[ks], bk, sacc[nt], 0, 0, 0);
    }
  float M[4];
  #pragma unroll
  for (int j = 0; j < 4; ++j) {
    float m = sacc[0][j];
    #pragma unroll
    for (int nt = 1; nt < 8; ++nt) m = fmaxf(m, sacc[nt][j]);
    m = fmaxf(m, __shfl_xor(m, 1));
    m = fmaxf(m, __shfl_xor(m, 2));
    m = fmaxf(m, __shfl_xor(m, 4));
    m = fmaxf(m, __shfl_xor(m, 8));
    M[j] = m;
  }
  __syncthreads();
  float Ssum[4] = {0.f, 0.f, 0.f, 0.f};
  #pragma unroll
  for (int nt = 0; nt < 8; ++nt)
    #pragma unroll
    for (int j = 0; j < 4; ++j) {
      float pf = __expf(sacc[nt][j] - M[j]);
      Ssum[j] += pf;
      Pl[w * 16 + (lane >> 4) * 4 + j][nt * 16 + (lane & 15)] = f2bf(pf);
    }
  #pragma unroll
  for (int j = 0; j < 4; ++j) {
    float s = Ssum[j];
    s += __shfl_xor(s, 1);
    s += __shfl_xor(s, 2);
    s += __shfl_xor(s, 4);
    s += __shfl_xor(s, 8);
    Ssum[j] = s;
  }
  if ((lane & 15) == 0) {
    #pragma unroll
    for (int j = 0; j < 4; ++j) {
      int l2 = w * 16 + (lane >> 4) * 4 + j;
      float* sp = stat + (((size_t)bh * 32 + ch) * 64 + l2) * 2;
      sp[0] = M[j]; sp[1] = Ssum[j];
    }
  }
  __syncthreads();
  f4ev oacc[4];
  #pragma unroll
  for (int nt = 0; nt < 4; ++nt) oacc[nt] = zz;
  #pragma unroll
  for (int ks = 0; ks < 4; ++ks) {
    bh8 ap = *(const bh8*)&Pl[w * 16 + (lane & 15)][ks * 32 + (lane >> 4) * 8];
    #pragma unroll
    for (int nt = 0; nt < 4; ++nt) {
      bh8 bv = *(const bh8*)&VT[nt * 16 + (lane & 15)][ks * 32 + (lane >> 4) * 8];
      oacc[nt] = __builtin_amdgcn_mfma_f32_16x16x32_bf16(ap, bv, oacc[nt], 0, 0, 0);
    }
  }
  float* ob = ocp + (((size_t)bh * 32 + ch) * 64) * 64;
  #pragma unroll
  for (int nt = 0; nt < 4; ++nt)
    #pragma unroll
    for (int j = 0; j < 4; ++j) {
      int l2 = w * 16 + ((lane >> 4) << 2) + j;
      ob[l2 * 64 + nt * 16 + (lane & 15)] = oacc[nt][j];
    }
}

// ---------- wide combine: 32 chunk partials -> normalized k3v (in chunk-0 slot) ----
__global__ void k3vcomb_k(float* __restrict__ ocp, const float* __restrict__ stat) {
  int bh = blockIdx.x, rg = blockIdx.y;
  int t = threadIdx.x;
  int row = rg * 4 + (t >> 6), col = t & 63;
  const float* sp = stat + (size_t)bh * 32 * 128 + row * 2;
  float M = -1e30f;
  #pragma unroll
  for (int c = 0; c < 32; ++c) M = fmaxf(M, sp[c * 128]);
  float S = 0.f;
  float wcb[32];
  #pragma unroll
  for (int c = 0; c < 32; ++c) {
    float wv = __expf(sp[c * 128] - M);
    wcb[c] = wv;
    S += wv * sp[c * 128 + 1];
  }
  float inv = 1.f / S;
  float* base = ocp + (size_t)bh * 32 * 4096 + row * 64 + col;
  float acc = 0.f;
  #pragma unroll
  for (int c = 0; c < 32; ++c) acc += base[(size_t)c * 4096] * wcb[c];
  *base = acc * inv;   // chunk-0 slot; this block exclusively owns these rows
}

// ---------- small matmul: W2 = Vinv @ k3v ----------
__global__ void w2m_k(const float* __restrict__ ocp, const float* __restrict__ vinv,
                      float* __restrict__ w2) {
  __shared__ float kv[64][72], vi[64][72];
  int bh = blockIdx.x, t = threadIdx.x, j = t & 63, ig = t >> 6;
  for (int i = t; i < 4096; i += 256) {
    kv[i >> 6][i & 63] = ocp[(size_t)bh * 32 * 4096 + i];
    vi[i >> 6][i & 63] = vinv[(size_t)bh * 4096 + i];
  }
  __syncthreads();
  float a[16];
  #pragma unroll
  for (int li = 0; li < 16; ++li) a[li] = 0.f;
  for (int c2 = 0; c2 < 64; ++c2) {
    float vv = kv[c2][j];
    #pragma unroll
    for (int li = 0; li < 16; ++li) a[li] += vi[ig * 16 + li][c2] * vv;
  }
  #pragma unroll
  for (int li = 0; li < 16; ++li) w2[(size_t)bh * 4096 + (ig * 16 + li) * 64 + j] = a[li];
}

// ---------- kernel_1 apply via MFMA: oh = softmax(q@kl^T) @ W2 ----------
__launch_bounds__(256)
__global__ void k1app_k(const __hip_bfloat16* __restrict__ qb, const float* __restrict__ kl,
                        const float* __restrict__ w2, __hip_bfloat16* __restrict__ oh) {
  __shared__ unsigned short SM[128 * 72 + 64 * 72 * 2];  // 36864 B
  auto Klhi = (unsigned short (*)[72])(SM);              // [64][72]
  auto Kllo = (unsigned short (*)[72])(SM + 64 * 72);    // [64][72]
  auto Pl   = (unsigned short (*)[72])(SM);              // [128][72], aliases Klhi+Kllo
  auto Whi  = (unsigned short (*)[72])(SM + 128 * 72);           // W2T hi [d][lm]
  auto Wlo  = (unsigned short (*)[72])(SM + 128 * 72 + 64 * 72); // W2T lo [d][lm]

  int ch = blockIdx.x, bh = blockIdx.y;
  int b = bh / Hn, h = bh % Hn;
  int t = threadIdx.x, lane = t & 63, w = t >> 6;

  {
    const float* klb = kl + (size_t)(b * Ln) * Cn + h * Dn;
    const float* w2b = w2 + (size_t)bh * 4096;
    #pragma unroll
    for (int it = 0; it < 4; ++it) {
      int idx = it * 256 + t;
      int l = idx >> 4, d0 = (idx & 15) * 4;
      float4 kv = *(const float4*)(klb + (size_t)l * Cn + d0);
      ushort4 hi4; ushort4 lo4;
      hi4.x = f2bf(kv.x); lo4.x = f2bf(kv.x - bf2f(hi4.x));
      hi4.y = f2bf(kv.y); lo4.y = f2bf(kv.y - bf2f(hi4.y));
      hi4.z = f2bf(kv.z); lo4.z = f2bf(kv.z - bf2f(hi4.z));
      hi4.w = f2bf(kv.w); lo4.w = f2bf(kv.w - bf2f(hi4.w));
      *(ushort4*)&Klhi[l][d0] = hi4;
      *(ushort4*)&Kllo[l][d0] = lo4;
      float4 wv = *(const float4*)(w2b + (size_t)l * 64 + d0);
      unsigned short h0 = f2bf(wv.x), h1 = f2bf(wv.y), h2 = f2bf(wv.z), h3 = f2bf(wv.w);
      Whi[d0 + 0][l] = h0; Wlo[d0 + 0][l] = f2bf(wv.x - bf2f(h0));
      Whi[d0 + 1][l] = h1; Wlo[d0 + 1][l] = f2bf(wv.y - bf2f(h1));
      Whi[d0 + 2][l] = h2; Wlo[d0 + 2][l] = f2bf(wv.z - bf2f(h2));
      Whi[d0 + 3][l] = h3; Wlo[d0 + 3][l] = f2bf(wv.w - bf2f(h3));
    }
  }
  bh8 aq[2][2];   // [m-tile][k-step]
  {
    const unsigned short* qbase = (const unsigned short*)qb + ((size_t)bh * Nn + (size_t)ch * 128) * Dn;
    #pragma unroll
    for (int m = 0; m < 2; ++m)
      #pragma unroll
      for (int ks = 0; ks < 2; ++ks)
        aq[m][ks] = *(const bh8*)(qbase + (size_t)(w * 32 + m * 16 + (lane & 15)) * Dn + ks * 32 + (lane >> 4) * 8);
  }
  __syncthreads();
  f4ev sacc[2][4];
  f4ev zz = {0.f, 0.f, 0.f, 0.f};
  #pragma unroll
  for (int m = 0; m < 2; ++m)
    #pragma unroll
    for (int nt = 0; nt < 4; ++nt) sacc[m][nt] = zz;
  #pragma unroll
  for (int ks = 0; ks < 2; ++ks)
    #pragma unroll
    for (int nt = 0; nt < 4; ++nt) {
      bh8 bhi = *(const bh8*)&Klhi[nt * 16 + (lane & 15)][ks * 32 + (lane >> 4) * 8];
      bh8 blo = *(const bh8*)&Kllo[nt * 16 + (lane & 15)][ks * 32 + (lane >> 4) * 8];
      #pragma unroll
      for (int m = 0; m < 2; ++m) {
        sacc[m][nt] = __builtin_amdgcn_mfma_f32_16x16x32_bf16(aq[m][ks], bhi, sacc[m][nt], 0, 0, 0);
        sacc[m][nt] = __builtin_amdgcn_mfma_f32_16x16x32_bf16(aq[m][ks], blo, sacc[m][nt], 0, 0, 0);
      }
    }
  float Pn[2][4][4];
  #pragma unroll
  for (int m = 0; m < 2; ++m)
    #pragma unroll
    for (int j = 0; j < 4; ++j) {
      float mx = sacc[m][0][j];
      #pragma unroll
      for (int nt = 1; nt < 4; ++nt) mx = fmaxf(mx, sacc[m][nt][j]);
      mx = fmaxf(mx, __shfl_xor(mx, 1));
      mx = fmaxf(mx, __shfl_xor(mx, 2));
      mx = fmaxf(mx, __shfl_xor(mx, 4));
      mx = fmaxf(mx, __shfl_xor(mx, 8));
      float sum = 0.f;
      #pragma unroll
      for (int nt = 0; nt < 4; ++nt) {
        float e = __expf(sacc[m][nt][j] - mx);
        Pn[m][nt][j] = e;
        sum += e;
      }
      sum += __shfl_xor(sum, 1);
      sum += __shfl_xor(sum, 2);
      sum += __shfl_xor(sum, 4);
      sum += __shfl_xor(sum, 8);
      float inv = 1.f / sum;
      #pragma unroll
      for (int nt = 0; nt < 4; ++nt) Pn[m][nt][j] *= inv;
    }
  __syncthreads();
  #pragma unroll
  for (int m = 0; m < 2; ++m)
    #pragma unroll
    for (int nt = 0; nt < 4; ++nt)
      #pragma unroll
      for (int j = 0; j < 4; ++j)
        Pl[w * 32 + m * 16 + (lane >> 4) * 4 + j][nt * 16 + (lane & 15)] = f2bf(Pn[m][nt][j]);
  __syncthreads();
  f4ev oacc[2][4];
  #pragma unroll
  for (int m = 0; m < 2; ++m)
    #pragma unroll
    for (int nt = 0; nt < 4; ++nt) oacc[m][nt] = zz;
  #pragma unroll
  for (int ks = 0; ks < 2; ++ks) {
    bh8 ap[2];
    #pragma unroll
    for (int m = 0; m < 2; ++m)
      ap[m] = *(const bh8*)&Pl[w * 32 + m * 16 + (lane & 15)][ks * 32 + (lane >> 4) * 8];
    #pragma unroll
    for (int nt = 0; nt < 4; ++nt) {
      bh8 bhi = *(const bh8*)&Whi[nt * 16 + (lane & 15)][ks * 32 + (lane >> 4) * 8];
      bh8 blo = *(const bh8*)&Wlo[nt * 16 + (lane & 15)][ks * 32 + (lane >> 4) * 8];
      #pragma unroll
      for (int m = 0; m < 2; ++m) {
        oacc[m][nt] = __builtin_amdgcn_mfma_f32_16x16x32_bf16(ap[m], bhi, oacc[m][nt], 0, 0, 0);
        oacc[m][nt] = __builtin_amdgcn_mfma_f32_16x16x32_bf16(ap[m], blo, oacc[m][nt], 0, 0, 0);
      }
    }
  }
  unsigned short* ohb = (unsigned short*)oh;
  #pragma unroll
  for (int m = 0; m < 2; ++m)
    #pragma unroll
    for (int nt = 0; nt < 4; ++nt)
      #pragma unroll
      for (int j = 0; j < 4; ++j) {
        int tok = ch * 128 + w * 32 + m * 16 + (lane >> 4) * 4 + j;
        int dd = nt * 16 + (lane & 15);
        ohb[((size_t)(b * Nn + tok)) * Cn + h * Dn + dd] = f2bf(oacc[m][nt][j]);
      }
}

// ---------- final projection: BK=32 swizzled, double-buffered ----------
__launch_bounds__(256)
__global__ void gemm_proj_k(const __hip_bfloat16* __restrict__ A, const __hip_bfloat16* __restrict__ W,
                            const float* __restrict__ bias, float* __restrict__ out) {
  __shared__ unsigned short As[2][128][32], Bs[2][128][32];
  int t = threadIdx.x, lane = t & 63, w = t >> 6;
  int wr = w >> 1, wc = w & 1;
  int m0 = blockIdx.x * 128, n0 = blockIdx.y * 128;
  int srow = lane >> 2;
  int scol = (((lane & 3) ^ ((lane >> 3) & 3))) * 8;
  int rcol = (((lane >> 4) ^ ((lane >> 1) & 3))) * 8;
  f4ev acc[4][4];
  f4ev zz = {0.f, 0.f, 0.f, 0.f};
  #pragma unroll
  for (int m = 0; m < 4; ++m)
    #pragma unroll
    for (int n = 0; n < 4; ++n) acc[m][n] = zz;
  const __hip_bfloat16* ga = A + (size_t)(m0 + w * 16 + srow) * Cn + scol;
  const __hip_bfloat16* gb = W + (size_t)(n0 + w * 16 + srow) * Cn + scol;

  gload_lds16(ga,                   &As[0][w * 16][0]);
  gload_lds16(ga + (size_t)64 * Cn, &As[0][64 + w * 16][0]);
  gload_lds16(gb,                   &Bs[0][w * 16][0]);
  gload_lds16(gb + (size_t)64 * Cn, &Bs[0][64 + w * 16][0]);
  __syncthreads();
  int cur = 0;
  for (int it = 0; it < 24; ++it) {
    if (it < 23) {
      int k0 = (it + 1) * 32;
      gload_lds16(ga + k0,                   &As[cur ^ 1][w * 16][0]);
      gload_lds16(ga + (size_t)64 * Cn + k0, &As[cur ^ 1][64 + w * 16][0]);
      gload_lds16(gb + k0,                   &Bs[cur ^ 1][w * 16][0]);
      gload_lds16(gb + (size_t)64 * Cn + k0, &Bs[cur ^ 1][64 + w * 16][0]);
    }
    bh8 af[4], bf_[4];
    #pragma unroll
    for (int m = 0; m < 4; ++m)
      af[m] = *(const bh8*)&As[cur][wr * 64 + m * 16 + (lane & 15)][rcol];
    #pragma unroll
    for (int n = 0; n < 4; ++n)
      bf_[n] = *(const bh8*)&Bs[cur][wc * 64 + n * 16 + (lane & 15)][rcol];
    #pragma unroll
    for (int m = 0; m < 4; ++m)
      #pragma unroll
      for (int n = 0; n < 4; ++n)
        acc[m][n] = __builtin_amdgcn_mfma_f32_16x16x32_bf16(af[m], bf_[n], acc[m][n], 0, 0, 0);
    __syncthreads();
    cur ^= 1;
  }
  #pragma unroll
  for (int m = 0; m < 4; ++m) {
    int rbase = m0 + wr * 64 + m * 16 + ((lane >> 4) << 2);
    #pragma unroll
    for (int n = 0; n < 4; ++n) {
      int c = n0 + wc * 64 + n * 16 + (lane & 15);
      float bv = bias[c];
      #pragma unroll
      for (int jj = 0; jj < 4; ++jj)
        out[(size_t)(rbase + jj) * Cn + c] = acc[m][n][jj] + bv;
    }
  }
}

extern "C" void kernel_launch(void* const* d_in, const int* in_sizes, int n_in,
                              void* d_out, int out_size, void* d_ws, size_t ws_size,
                              hipStream_t stream) {
  const float* x     = (const float*)d_in[0];
  const float* wqkv  = (const float*)d_in[1];
  const float* wproj = (const float*)d_in[2];
  const float* bproj = (const float*)d_in[3];
  float* out = (float*)d_out;
  char* ws = (char*)d_ws;

  auto xb   = (__hip_bfloat16*)(ws + OFF_XB);
  auto qb   = (__hip_bfloat16*)(ws + OFF_QB);
  auto kb   = (__hip_bfloat16*)(ws + OFF_KB);
  auto vb   = (__hip_bfloat16*)(ws + OFF_VB);
  auto wqb  = (__hip_bfloat16*)(ws + OFF_WQB);
  auto wpb  = (__hip_bfloat16*)(ws + OFF_WPB);
  auto ocp  = (float*)(ws + OFF_XB);            // alias: xb dead after gemm_qkv
  auto oh   = (__hip_bfloat16*)(ws + OFF_XB);   // alias: ocp dead after w2m
  auto part = (float*)(ws + OFF_QB);            // alias: qb not yet written
  auto xm   = (float*)(ws + OFF_XM);
  auto ql   = (float*)(ws + OFF_QL);
  auto kl   = (float*)(ws + OFF_KL);
  auto vinv = (float*)(ws + OFF_VINV);
  auto cp   = (float*)(ws + OFF_CP);
  auto w2   = (float*)(ws + OFF_W2);

  castmean_k<<<dim3(256, 2), 192, 0, stream>>>(x, (unsigned short*)xb, xm);
  cast_k<<<1024, 256, 0, stream>>>(wqkv, (unsigned short*)wqb, 3 * Cn * Cn / 4);
  cast_k<<<512, 256, 0, stream>>>(wproj, (unsigned short*)wpb, Cn * Cn / 4);
  landgemm_k<<<dim3(4, 24, 12), 256, 0, stream>>>(xm, wqkv, part);
  landred_k<<<384, 256, 0, stream>>>(part, ql, kl);
  k2inv_k<<<48, 256, 0, stream>>>(ql, kl, vinv);
  gemm_qkv_k<<<dim3(128, 18), 256, 0, stream>>>(xb, wqb, qb, kb, vb);
  k3vflash_k<<<dim3(32, 48), 256, 0, stream>>>(ql, kb, vb, ocp, cp);
  k3vcomb_k<<<dim3(48, 16), 256, 0, stream>>>(ocp, cp);
  w2m_k<<<48, 256, 0, stream>>>(ocp, vinv, w2);
  k1app_k<<<dim3(32, 48), 256, 0, stream>>>(qb, kl, w2, oh);
  gemm_proj_k<<<dim3(128, 6), 256, 0, stream>>>(oh, wpb, bproj, out);
}

// Round 16
// 255.649 us; speedup vs baseline: 1.0610x; 1.0610x over previous
//
#include <hip/hip_runtime.h>
#include <hip/hip_bf16.h>

#define DI __device__ __forceinline__

typedef __attribute__((ext_vector_type(8))) short bh8;   // 8 bf16 (4 VGPR) MFMA frag
typedef __attribute__((ext_vector_type(8))) unsigned short us8;
typedef __attribute__((ext_vector_type(4))) float f4ev;  // MFMA f32 accumulator

static constexpr int Bn = 4;
static constexpr int Nn = 4096;
static constexpr int Cn = 768;
static constexpr int Hn = 12;
static constexpr int Dn = 64;    // head dim
static constexpr int Ln = 64;    // landmarks
static constexpr int TOKS = Bn * Nn;   // 16384
static constexpr int BHn = Bn * Hn;    // 48

// ---- workspace layout (bytes); stays within the proven ~110 MB footprint ----
static constexpr size_t SZ_XB  = (size_t)TOKS * Cn * 2;       // 25165824
static constexpr size_t SZ_QKV = (size_t)BHn * Nn * Dn * 2;   // 25165824
static constexpr size_t OFF_XB   = 0;                         // xb; later ocp; later oh
static constexpr size_t OFF_QB   = OFF_XB + SZ_XB;            // land partials live here pre-gemm_qkv
static constexpr size_t OFF_KB   = OFF_QB + SZ_QKV;
static constexpr size_t OFF_VB   = OFF_KB + SZ_QKV;
static constexpr size_t OFF_WQB  = OFF_VB + SZ_QKV;
static constexpr size_t OFF_WPB  = OFF_WQB + (size_t)3 * Cn * Cn * 2;
static constexpr size_t OFF_XM   = OFF_WPB + (size_t)Cn * Cn * 2;
static constexpr size_t OFF_QL   = OFF_XM + (size_t)Bn * Ln * Cn * 4;
static constexpr size_t OFF_KL   = OFF_QL + (size_t)Bn * Ln * Cn * 4;
static constexpr size_t OFF_VINV = OFF_KL + (size_t)Bn * Ln * Cn * 4;
static constexpr size_t OFF_CP   = OFF_VINV + (size_t)BHn * 64 * 64 * 4;  // stats: 48*32*64*2 f32
static constexpr size_t OFF_W2   = OFF_CP + (size_t)BHn * 32 * 64 * 2 * 4;

DI unsigned short f2bf(float f) {
  __hip_bfloat16 h = __float2bfloat16(f);
  return *reinterpret_cast<unsigned short*>(&h);
}
DI float bf2f(unsigned short u) {
  union { unsigned int i; float f; } c; c.i = ((unsigned)u) << 16; return c.f;
}

DI void gload_lds16(const void* g, void* l) {
  __builtin_amdgcn_global_load_lds((const __attribute__((address_space(1))) void*)g,
                                   (__attribute__((address_space(3))) void*)l, 16, 0, 0);
}

// ---------- cast both weight matrices (wqkv then wproj) in one launch ----------
__global__ void castw_k(const float* __restrict__ wqkv, const float* __restrict__ wproj,
                        unsigned short* __restrict__ dq, unsigned short* __restrict__ dp) {
  const int nq = 3 * Cn * Cn / 4;      // 442368 float4s
  const int np = Cn * Cn / 4;          // 147456 float4s
  int i = blockIdx.x * blockDim.x + threadIdx.x;
  int st = gridDim.x * blockDim.x;
  for (; i < nq + np; i += st) {
    const float4* s4;
    ushort4* d4;
    int idx;
    if (i < nq) { s4 = (const float4*)wqkv;  d4 = (ushort4*)dq; idx = i; }
    else        { s4 = (const float4*)wproj; d4 = (ushort4*)dp; idx = i - nq; }
    float4 v = s4[idx];
    ushort4 o; o.x = f2bf(v.x); o.y = f2bf(v.y); o.z = f2bf(v.z); o.w = f2bf(v.w);
    d4[idx] = o;
  }
}

// ---------- fused: cast x -> bf16 AND exact f32 segment-mean -> xm ----------
__global__ void castmean_k(const float* __restrict__ x, unsigned short* __restrict__ xb,
                           float* __restrict__ xm) {
  int bl = blockIdx.x, cz = blockIdx.y;
  int c = cz * 384 + threadIdx.x * 2;
  const float* xp = x + (size_t)bl * 64 * Cn + c;
  unsigned short* xbp = xb + (size_t)bl * 64 * Cn + c;
  float s0 = 0.f, s1 = 0.f;
  #pragma unroll 8
  for (int r = 0; r < 64; ++r) {
    float2 v = *(const float2*)(xp + (size_t)r * Cn);
    ushort2 o; o.x = f2bf(v.x); o.y = f2bf(v.y);
    *(ushort2*)(xbp + (size_t)r * Cn) = o;
    s0 += v.x; s1 += v.y;
  }
  xm[(size_t)bl * Cn + c]     = s0 * 0.015625f;
  xm[(size_t)bl * Cn + c + 1] = s1 * 0.015625f;
}

// ---------- landmark projection, K-split x12, register-blocked 4x4 ----------
__launch_bounds__(256)
__global__ void landgemm_k(const float* __restrict__ xm, const float* __restrict__ wqkv,
                           float* __restrict__ part) {
  __shared__ float XT[64][65];
  __shared__ float WT[64][65];
  int b = blockIdx.x, ct = blockIdx.y, kc = blockIdx.z;
  int t = threadIdx.x;
  int tr = t >> 4, tc = t & 15;
  int r0 = tr * 4, j0 = tc * 4;
  const float* xb_ = xm + (size_t)b * Ln * Cn + kc * 64;
  const float* wb_ = wqkv + (size_t)ct * 64 * Cn + kc * 64;
  #pragma unroll
  for (int i = t; i < 1024; i += 256) {
    int r = i >> 4, c4 = (i & 15) * 4;
    float4 xv = *(const float4*)(xb_ + (size_t)r * Cn + c4);
    XT[c4 + 0][r] = xv.x; XT[c4 + 1][r] = xv.y; XT[c4 + 2][r] = xv.z; XT[c4 + 3][r] = xv.w;
    float4 wv = *(const float4*)(wb_ + (size_t)r * Cn + c4);
    WT[c4 + 0][r] = wv.x; WT[c4 + 1][r] = wv.y; WT[c4 + 2][r] = wv.z; WT[c4 + 3][r] = wv.w;
  }
  __syncthreads();
  float acc[4][4];
  #pragma unroll
  for (int i = 0; i < 4; ++i)
    #pragma unroll
    for (int j = 0; j < 4; ++j) acc[i][j] = 0.f;
  for (int cc = 0; cc < 64; ++cc) {
    float4 a4 = *(const float4*)&XT[cc][r0];
    float4 b4 = *(const float4*)&WT[cc][j0];
    acc[0][0] += a4.x * b4.x; acc[0][1] += a4.x * b4.y; acc[0][2] += a4.x * b4.z; acc[0][3] += a4.x * b4.w;
    acc[1][0] += a4.y * b4.x; acc[1][1] += a4.y * b4.y; acc[1][2] += a4.y * b4.z; acc[1][3] += a4.y * b4.w;
    acc[2][0] += a4.z * b4.x; acc[2][1] += a4.z * b4.y; acc[2][2] += a4.z * b4.z; acc[2][3] += a4.z * b4.w;
    acc[3][0] += a4.w * b4.x; acc[3][1] += a4.w * b4.y; acc[3][2] += a4.w * b4.z; acc[3][3] += a4.w * b4.w;
  }
  float* op = part + ((size_t)kc * 256 + b * Ln) * 1536 + (size_t)ct * 64;
  #pragma unroll
  for (int i = 0; i < 4; ++i)
    *(float4*)(op + (size_t)(r0 + i) * 1536 + j0) = make_float4(acc[i][0], acc[i][1], acc[i][2], acc[i][3]);
}

// ---------- sum 12 K-split partials -> ql (x0.125), kl ----------
__global__ void landred_k(const float* __restrict__ part, float* __restrict__ ql,
                          float* __restrict__ kl) {
  int i4 = blockIdx.x * 256 + threadIdx.x;
  const float4* p4 = (const float4*)part;
  float4 s = p4[i4];
  #pragma unroll
  for (int kc = 1; kc < 12; ++kc) {
    float4 v = p4[(size_t)kc * 98304 + i4];
    s.x += v.x; s.y += v.y; s.z += v.z; s.w += v.w;
  }
  int row = i4 / 384, c = (i4 % 384) * 4;
  if (c < 768) {
    s.x *= 0.125f; s.y *= 0.125f; s.z *= 0.125f; s.w *= 0.125f;
    *(float4*)(ql + (size_t)row * Cn + c) = s;
  } else {
    *(float4*)(kl + (size_t)row * Cn + (c - 768)) = s;
  }
}

// ---------- kernel_2 softmax + 6-iter Newton-Schulz inverse ----------
__launch_bounds__(256)
__global__ void k2inv_k(const float* __restrict__ ql, const float* __restrict__ kl,
                        float* __restrict__ vinv) {
  __shared__ float B0[64][68], B1[64][68], B2[64][68], B3[64][68],
                   B4[64][68], B5[64][68], B6[64][68], B7[64][68];
  __shared__ float dinv_s;
  float (*Qt)[68] = B0, (*Kt)[68] = B1;
  float (*KV)[68] = B0, (*KVt)[68] = B1;
  float (*K2)[68] = B2, (*K2t)[68] = B3;
  float (*Vv)[68] = B4, (*Vt)[68] = B5;
  float (*T1)[68] = B6, (*Uu)[68] = B7;

  int bh = blockIdx.x, b = bh / Hn, h = bh % Hn;
  int t = threadIdx.x;
  int tr = t >> 4, tc = t & 15;
  int r0 = tr * 4, j0 = tc * 4;

  {
    const float* qbase = ql + (size_t)(b * Ln) * Cn + h * Dn;
    const float* kbase = kl + (size_t)(b * Ln) * Cn + h * Dn;
    #pragma unroll
    for (int it = 0; it < 4; ++it) {
      int idx = it * 256 + t;
      int l = idx >> 4, d0 = (idx & 15) * 4;
      float4 qv = *(const float4*)(qbase + (size_t)l * Cn + d0);
      float4 kv = *(const float4*)(kbase + (size_t)l * Cn + d0);
      Qt[d0 + 0][l] = qv.x; Qt[d0 + 1][l] = qv.y; Qt[d0 + 2][l] = qv.z; Qt[d0 + 3][l] = qv.w;
      Kt[d0 + 0][l] = kv.x; Kt[d0 + 1][l] = kv.y; Kt[d0 + 2][l] = kv.z; Kt[d0 + 3][l] = kv.w;
    }
  }
  __syncthreads();

  float acc[4][4];
  #define MM64(LT, RR)                                                     \
    {                                                                      \
      _Pragma("unroll")                                                    \
      for (int i_ = 0; i_ < 4; ++i_)                                       \
        _Pragma("unroll")                                                  \
        for (int j_ = 0; j_ < 4; ++j_) acc[i_][j_] = 0.f;                  \
      for (int c_ = 0; c_ < 64; c_ += 4) {                                 \
        _Pragma("unroll")                                                  \
        for (int cc_ = 0; cc_ < 4; ++cc_) {                                \
          float4 a4 = *(const float4*)&LT[c_ + cc_][r0];                   \
          float4 b4 = *(const float4*)&RR[c_ + cc_][j0];                   \
          acc[0][0] += a4.x * b4.x; acc[0][1] += a4.x * b4.y;              \
          acc[0][2] += a4.x * b4.z; acc[0][3] += a4.x * b4.w;              \
          acc[1][0] += a4.y * b4.x; acc[1][1] += a4.y * b4.y;              \
          acc[1][2] += a4.y * b4.z; acc[1][3] += a4.y * b4.w;              \
          acc[2][0] += a4.z * b4.x; acc[2][1] += a4.z * b4.y;              \
          acc[2][2] += a4.z * b4.z; acc[2][3] += a4.z * b4.w;              \
          acc[3][0] += a4.w * b4.x; acc[3][1] += a4.w * b4.y;              \
          acc[3][2] += a4.w * b4.z; acc[3][3] += a4.w * b4.w;              \
        }                                                                  \
      }                                                                    \
    }

  MM64(Qt, Kt);
  #pragma unroll
  for (int i = 0; i < 4; ++i)
    *(float4*)&K2[r0 + i][j0] = make_float4(acc[i][0], acc[i][1], acc[i][2], acc[i][3]);
  __syncthreads();

  if (t < 64) {
    float m = -1e30f;
    #pragma unroll
    for (int c4 = 0; c4 < 16; ++c4) {
      float4 v = *(const float4*)&K2[t][c4 * 4];
      m = fmaxf(m, fmaxf(fmaxf(v.x, v.y), fmaxf(v.z, v.w)));
    }
    float s = 0.f;
    #pragma unroll
    for (int c4 = 0; c4 < 16; ++c4) {
      float4 v = *(const float4*)&K2[t][c4 * 4];
      v.x = __expf(v.x - m); v.y = __expf(v.y - m);
      v.z = __expf(v.z - m); v.w = __expf(v.w - m);
      s += v.x + v.y + v.z + v.w;
      *(float4*)&K2[t][c4 * 4] = v;
    }
    float inv = 1.f / s;
    #pragma unroll
    for (int c4 = 0; c4 < 16; ++c4) {
      float4 v = *(const float4*)&K2[t][c4 * 4];
      v.x *= inv; v.y *= inv; v.z *= inv; v.w *= inv;
      *(float4*)&K2[t][c4 * 4] = v;
      K2t[c4 * 4 + 0][t] = v.x; K2t[c4 * 4 + 1][t] = v.y;
      K2t[c4 * 4 + 2][t] = v.z; K2t[c4 * 4 + 3][t] = v.w;
    }
  }
  __syncthreads();
  if (t < 64) {
    float cs = 0.f;
    #pragma unroll
    for (int c4 = 0; c4 < 16; ++c4) {
      float4 v = *(const float4*)&K2t[t][c4 * 4];
      cs += v.x + v.y + v.z + v.w;
    }
    #pragma unroll
    for (int off = 1; off < 64; off <<= 1) cs = fmaxf(cs, __shfl_xor(cs, off));
    if (t == 0) dinv_s = 1.f / cs;
  }
  __syncthreads();
  float dinv = dinv_s;
  #pragma unroll
  for (int jj = 0; jj < 4; ++jj) {
    float4 k4 = *(const float4*)&K2[j0 + jj][r0];
    k4.x *= dinv; k4.y *= dinv; k4.z *= dinv; k4.w *= dinv;
    *(float4*)&Vt[j0 + jj][r0] = k4;
    Vv[r0 + 0][j0 + jj] = k4.x; Vv[r0 + 1][j0 + jj] = k4.y;
    Vv[r0 + 2][j0 + jj] = k4.z; Vv[r0 + 3][j0 + jj] = k4.w;
  }
  __syncthreads();

  float nv[4][4];
  for (int itn = 0; itn < 6; ++itn) {
    MM64(K2t, Vv);
    #pragma unroll
    for (int i = 0; i < 4; ++i)
      *(float4*)&KV[r0 + i][j0] = make_float4(acc[i][0], acc[i][1], acc[i][2], acc[i][3]);
    #pragma unroll
    for (int jj = 0; jj < 4; ++jj)
      *(float4*)&KVt[j0 + jj][r0] = make_float4(acc[0][jj], acc[1][jj], acc[2][jj], acc[3][jj]);
    __syncthreads();
    MM64(KVt, KV);
    #pragma unroll
    for (int i = 0; i < 4; ++i) {
      float4 kv4 = *(const float4*)&KV[r0 + i][j0];
      *(float4*)&T1[r0 + i][j0] = make_float4(7.f * kv4.x - acc[i][0], 7.f * kv4.y - acc[i][1],
                                              7.f * kv4.z - acc[i][2], 7.f * kv4.w - acc[i][3]);
    }
    __syncthreads();
    MM64(KVt, T1);
    #pragma unroll
    for (int i = 0; i < 4; ++i) {
      float4 kv4 = *(const float4*)&KV[r0 + i][j0];
      *(float4*)&Uu[r0 + i][j0] = make_float4(15.f * kv4.x - acc[i][0], 15.f * kv4.y - acc[i][1],
                                              15.f * kv4.z - acc[i][2], 15.f * kv4.w - acc[i][3]);
    }
    __syncthreads();
    MM64(Vt, Uu);
    #pragma unroll
    for (int i = 0; i < 4; ++i) {
      float4 v4 = *(const float4*)&Vv[r0 + i][j0];
      nv[i][0] = 0.25f * (13.f * v4.x - acc[i][0]);
      nv[i][1] = 0.25f * (13.f * v4.y - acc[i][1]);
      nv[i][2] = 0.25f * (13.f * v4.z - acc[i][2]);
      nv[i][3] = 0.25f * (13.f * v4.w - acc[i][3]);
    }
    __syncthreads();
    #pragma unroll
    for (int i = 0; i < 4; ++i)
      *(float4*)&Vv[r0 + i][j0] = make_float4(nv[i][0], nv[i][1], nv[i][2], nv[i][3]);
    #pragma unroll
    for (int jj = 0; jj < 4; ++jj)
      *(float4*)&Vt[j0 + jj][r0] = make_float4(nv[0][jj], nv[1][jj], nv[2][jj], nv[3][jj]);
    __syncthreads();
  }
  float* op = vinv + (size_t)bh * 4096;
  #pragma unroll
  for (int i = 0; i < 4; ++i)
    *(float4*)(op + (size_t)(r0 + i) * 64 + j0) = make_float4(nv[i][0], nv[i][1], nv[i][2], nv[i][3]);
  #undef MM64
}

// ---------- big GEMM: BK=64 double-buffered 2-phase pipeline (R13-proven) ----------
__launch_bounds__(256)
__global__ void gemm_qkv_k(const __hip_bfloat16* __restrict__ A, const __hip_bfloat16* __restrict__ W,
                           __hip_bfloat16* __restrict__ qb, __hip_bfloat16* __restrict__ kb,
                           __hip_bfloat16* __restrict__ vb) {
  __shared__ unsigned short As[2][128][64], Bs[2][128][64];   // 64 KB
  int t = threadIdx.x, lane = t & 63, w = t >> 6;
  int wr = w >> 1, wc = w & 1;
  int m0 = blockIdx.x * 128, n0 = blockIdx.y * 128;
  int srow = w * 8 + (lane >> 3);
  int scol = ((lane & 7) ^ ((lane >> 3) & 7)) * 8;       // pre-swizzled source col
  f4ev acc[4][4];
  f4ev zz = {0.f, 0.f, 0.f, 0.f};
  #pragma unroll
  for (int m = 0; m < 4; ++m)
    #pragma unroll
    for (int n = 0; n < 4; ++n) acc[m][n] = zz;
  const __hip_bfloat16* ga = A + (size_t)(m0 + srow) * Cn + scol;
  const __hip_bfloat16* gb = W + (size_t)(n0 + srow) * Cn + scol;

  #pragma unroll
  for (int c = 0; c < 4; ++c) {
    gload_lds16(ga + (size_t)(c * 32) * Cn, &As[0][c * 32 + w * 8][0]);
    gload_lds16(gb + (size_t)(c * 32) * Cn, &Bs[0][c * 32 + w * 8][0]);
  }
  __syncthreads();
  int cur = 0;
  for (int it = 0; it < 12; ++it) {
    if (it < 11) {
      int k0 = (it + 1) * 64;
      #pragma unroll
      for (int c = 0; c < 4; ++c) {
        gload_lds16(ga + (size_t)(c * 32) * Cn + k0, &As[cur ^ 1][c * 32 + w * 8][0]);
        gload_lds16(gb + (size_t)(c * 32) * Cn + k0, &Bs[cur ^ 1][c * 32 + w * 8][0]);
      }
    }
    #pragma unroll
    for (int ks = 0; ks < 2; ++ks) {
      int pc = ((ks * 4 + (lane >> 4)) ^ (lane & 7)) * 8;  // swizzled read col
      bh8 af[4], bf_[4];
      #pragma unroll
      for (int m = 0; m < 4; ++m)
        af[m] = *(const bh8*)&As[cur][wr * 64 + m * 16 + (lane & 15)][pc];
      #pragma unroll
      for (int n = 0; n < 4; ++n)
        bf_[n] = *(const bh8*)&Bs[cur][wc * 64 + n * 16 + (lane & 15)][pc];
      #pragma unroll
      for (int m = 0; m < 4; ++m)
        #pragma unroll
        for (int n = 0; n < 4; ++n)
          acc[m][n] = __builtin_amdgcn_mfma_f32_16x16x32_bf16(af[m], bf_[n], acc[m][n], 0, 0, 0);
    }
    __syncthreads();
    cur ^= 1;
  }
  int which = (n0 >= 1536) ? 2 : (n0 >= 768 ? 1 : 0);
  __hip_bfloat16* dst = which == 0 ? qb : (which == 1 ? kb : vb);
  float sc = which == 0 ? 0.125f : 1.f;
  #pragma unroll
  for (int m = 0; m < 4; ++m) {
    int rbase = m0 + wr * 64 + m * 16 + ((lane >> 4) << 2);
    #pragma unroll
    for (int n = 0; n < 4; ++n) {
      int c = n0 + wc * 64 + n * 16 + (lane & 15);
      int rem = c - which * 768;
      int h = rem >> 6, dd = rem & 63;
      #pragma unroll
      for (int jj = 0; jj < 4; ++jj) {
        int r = rbase + jj;
        int b = r >> 12, ntok = r & 4095;
        dst[(((size_t)(b * Hn + h) * Nn + ntok) << 6) + dd] = __float2bfloat16(acc[m][n][jj] * sc);
      }
    }
  }
}

// ---------- fused flash-style kernel_3 softmax + @v over 128-token chunks ----------
__launch_bounds__(256)
__global__ void k3vflash_k(const float* __restrict__ ql, const __hip_bfloat16* __restrict__ kb,
                           const __hip_bfloat16* __restrict__ vb,
                           float* __restrict__ ocp, float* __restrict__ stat) {
  __shared__ unsigned short Ks[128][72];   // K tile [token][d]; reused as Pl[64][136]
  __shared__ unsigned short VT[64][136];   // V^T tile [d][token]
  auto Pl = (unsigned short (*)[136]) & Ks[0][0];
  int ch = blockIdx.x, bh = blockIdx.y;
  int b = bh / Hn, h = bh % Hn;
  int t = threadIdx.x, lane = t & 63, w = t >> 6;

  {
    int row = t >> 1, half = (t & 1) * 32;
    const us8* krow = (const us8*)((const unsigned short*)kb + ((size_t)bh * Nn + (size_t)ch * 128 + row) * Dn + half);
    const us8* vrow = (const us8*)((const unsigned short*)vb + ((size_t)bh * Nn + (size_t)ch * 128 + row) * Dn + half);
    us8 kv0 = krow[0], kv1 = krow[1], kv2 = krow[2], kv3 = krow[3];
    us8 vv0 = vrow[0], vv1 = vrow[1], vv2 = vrow[2], vv3 = vrow[3];
    *(us8*)&Ks[row][half + 0]  = kv0;
    *(us8*)&Ks[row][half + 8]  = kv1;
    *(us8*)&Ks[row][half + 16] = kv2;
    *(us8*)&Ks[row][half + 24] = kv3;
    #pragma unroll
    for (int e = 0; e < 8; ++e) {
      VT[half + e][row]      = vv0[e];
      VT[half + 8 + e][row]  = vv1[e];
      VT[half + 16 + e][row] = vv2[e];
      VT[half + 24 + e][row] = vv3[e];
    }
  }
  bh8 aq[2];
  {
    const float* qrow = ql + ((size_t)(b * Ln + w * 16 + (lane & 15))) * Cn + h * Dn + (lane >> 4) * 8;
    #pragma unroll
    for (int ks = 0; ks < 2; ++ks) {
      float4 f0 = *(const float4*)(qrow + ks * 32);
      float4 f1 = *(const float4*)(qrow + ks * 32 + 4);
      bh8 v;
      v[0] = (short)f2bf(f0.x); v[1] = (short)f2bf(f0.y); v[2] = (short)f2bf(f0.z); v[3] = (short)f2bf(f0.w);
      v[4] = (short)f2bf(f1.x); v[5] = (short)f2bf(f1.y); v[6] = (short)f2bf(f1.z); v[7] = (short)f2bf(f1.w);
      aq[ks] = v;
    }
  }
  __syncthreads();
  f4ev sacc[8];
  f4ev zz = {0.f, 0.f, 0.f, 0.f};
  #pragma unroll
  for (int nt = 0; nt < 8; ++nt) sacc[nt] = zz;
  #pragma unroll
  for (int ks = 0; ks < 2; ++ks)
    #pragma unroll
    for (int nt = 0; nt < 8; ++nt) {
      bh8 bk = *(const bh8*)&Ks[nt * 16 + (lane & 15)][ks * 32 + (lane >> 4) * 8];
      sacc[nt] = __builtin_amdgcn_mfma_f32_16x16x32_bf16(aq[ks], bk, sacc[nt], 0, 0, 0);
    }
  float M[4];
  #pragma unroll
  for (int j = 0; j < 4; ++j) {
    float m = sacc[0][j];
    #pragma unroll
    for (int nt = 1; nt < 8; ++nt) m = fmaxf(m, sacc[nt][j]);
    m = fmaxf(m, __shfl_xor(m, 1));
    m = fmaxf(m, __shfl_xor(m, 2));
    m = fmaxf(m, __shfl_xor(m, 4));
    m = fmaxf(m, __shfl_xor(m, 8));
    M[j] = m;
  }
  __syncthreads();
  float Ssum[4] = {0.f, 0.f, 0.f, 0.f};
  #pragma unroll
  for (int nt = 0; nt < 8; ++nt)
    #pragma unroll
    for (int j = 0; j < 4; ++j) {
      float pf = __expf(sacc[nt][j] - M[j]);
      Ssum[j] += pf;
      Pl[w * 16 + (lane >> 4) * 4 + j][nt * 16 + (lane & 15)] = f2bf(pf);
    }
  #pragma unroll
  for (int j = 0; j < 4; ++j) {
    float s = Ssum[j];
    s += __shfl_xor(s, 1);
    s += __shfl_xor(s, 2);
    s += __shfl_xor(s, 4);
    s += __shfl_xor(s, 8);
    Ssum[j] = s;
  }
  if ((lane & 15) == 0) {
    #pragma unroll
    for (int j = 0; j < 4; ++j) {
      int l2 = w * 16 + (lane >> 4) * 4 + j;
      float* sp = stat + (((size_t)bh * 32 + ch) * 64 + l2) * 2;
      sp[0] = M[j]; sp[1] = Ssum[j];
    }
  }
  __syncthreads();
  f4ev oacc[4];
  #pragma unroll
  for (int nt = 0; nt < 4; ++nt) oacc[nt] = zz;
  #pragma unroll
  for (int ks = 0; ks < 4; ++ks) {
    bh8 ap = *(const bh8*)&Pl[w * 16 + (lane & 15)][ks * 32 + (lane >> 4) * 8];
    #pragma unroll
    for (int nt = 0; nt < 4; ++nt) {
      bh8 bv = *(const bh8*)&VT[nt * 16 + (lane & 15)][ks * 32 + (lane >> 4) * 8];
      oacc[nt] = __builtin_amdgcn_mfma_f32_16x16x32_bf16(ap, bv, oacc[nt], 0, 0, 0);
    }
  }
  float* ob = ocp + (((size_t)bh * 32 + ch) * 64) * 64;
  #pragma unroll
  for (int nt = 0; nt < 4; ++nt)
    #pragma unroll
    for (int j = 0; j < 4; ++j) {
      int l2 = w * 16 + ((lane >> 4) << 2) + j;
      ob[l2 * 64 + nt * 16 + (lane & 15)] = oacc[nt][j];
    }
}

// ---------- wide combine: 32 chunk partials -> normalized k3v (in chunk-0 slot) ----
__global__ void k3vcomb_k(float* __restrict__ ocp, const float* __restrict__ stat) {
  int bh = blockIdx.x, rg = blockIdx.y;
  int t = threadIdx.x;
  int row = rg * 4 + (t >> 6), col = t & 63;
  const float* sp = stat + (size_t)bh * 32 * 128 + row * 2;
  float M = -1e30f;
  #pragma unroll
  for (int c = 0; c < 32; ++c) M = fmaxf(M, sp[c * 128]);
  float S = 0.f;
  float wcb[32];
  #pragma unroll
  for (int c = 0; c < 32; ++c) {
    float wv = __expf(sp[c * 128] - M);
    wcb[c] = wv;
    S += wv * sp[c * 128 + 1];
  }
  float inv = 1.f / S;
  float* base = ocp + (size_t)bh * 32 * 4096 + row * 64 + col;
  float acc = 0.f;
  #pragma unroll
  for (int c = 0; c < 32; ++c) acc += base[(size_t)c * 4096] * wcb[c];
  *base = acc * inv;   // chunk-0 slot; this block exclusively owns these rows
}

// ---------- small matmul: W2 = Vinv @ k3v ----------
__global__ void w2m_k(const float* __restrict__ ocp, const float* __restrict__ vinv,
                      float* __restrict__ w2) {
  __shared__ float kv[64][72], vi[64][72];
  int bh = blockIdx.x, t = threadIdx.x, j = t & 63, ig = t >> 6;
  for (int i = t; i < 4096; i += 256) {
    kv[i >> 6][i & 63] = ocp[(size_t)bh * 32 * 4096 + i];
    vi[i >> 6][i & 63] = vinv[(size_t)bh * 4096 + i];
  }
  __syncthreads();
  float a[16];
  #pragma unroll
  for (int li = 0; li < 16; ++li) a[li] = 0.f;
  for (int c2 = 0; c2 < 64; ++c2) {
    float vv = kv[c2][j];
    #pragma unroll
    for (int li = 0; li < 16; ++li) a[li] += vi[ig * 16 + li][c2] * vv;
  }
  #pragma unroll
  for (int li = 0; li < 16; ++li) w2[(size_t)bh * 4096 + (ig * 16 + li) * 64 + j] = a[li];
}

// ---------- kernel_1 apply via MFMA: oh = softmax(q@kl^T) @ W2 ----------
__launch_bounds__(256)
__global__ void k1app_k(const __hip_bfloat16* __restrict__ qb, const float* __restrict__ kl,
                        const float* __restrict__ w2, __hip_bfloat16* __restrict__ oh) {
  __shared__ unsigned short SM[128 * 72 + 64 * 72 * 2];  // 36864 B
  auto Klhi = (unsigned short (*)[72])(SM);              // [64][72]
  auto Kllo = (unsigned short (*)[72])(SM + 64 * 72);    // [64][72]
  auto Pl   = (unsigned short (*)[72])(SM);              // [128][72], aliases Klhi+Kllo
  auto Whi  = (unsigned short (*)[72])(SM + 128 * 72);           // W2T hi [d][lm]
  auto Wlo  = (unsigned short (*)[72])(SM + 128 * 72 + 64 * 72); // W2T lo [d][lm]

  int ch = blockIdx.x, bh = blockIdx.y;
  int b = bh / Hn, h = bh % Hn;
  int t = threadIdx.x, lane = t & 63, w = t >> 6;

  {
    const float* klb = kl + (size_t)(b * Ln) * Cn + h * Dn;
    const float* w2b = w2 + (size_t)bh * 4096;
    #pragma unroll
    for (int it = 0; it < 4; ++it) {
      int idx = it * 256 + t;
      int l = idx >> 4, d0 = (idx & 15) * 4;
      float4 kv = *(const float4*)(klb + (size_t)l * Cn + d0);
      ushort4 hi4; ushort4 lo4;
      hi4.x = f2bf(kv.x); lo4.x = f2bf(kv.x - bf2f(hi4.x));
      hi4.y = f2bf(kv.y); lo4.y = f2bf(kv.y - bf2f(hi4.y));
      hi4.z = f2bf(kv.z); lo4.z = f2bf(kv.z - bf2f(hi4.z));
      hi4.w = f2bf(kv.w); lo4.w = f2bf(kv.w - bf2f(hi4.w));
      *(ushort4*)&Klhi[l][d0] = hi4;
      *(ushort4*)&Kllo[l][d0] = lo4;
      float4 wv = *(const float4*)(w2b + (size_t)l * 64 + d0);
      unsigned short h0 = f2bf(wv.x), h1 = f2bf(wv.y), h2 = f2bf(wv.z), h3 = f2bf(wv.w);
      Whi[d0 + 0][l] = h0; Wlo[d0 + 0][l] = f2bf(wv.x - bf2f(h0));
      Whi[d0 + 1][l] = h1; Wlo[d0 + 1][l] = f2bf(wv.y - bf2f(h1));
      Whi[d0 + 2][l] = h2; Wlo[d0 + 2][l] = f2bf(wv.z - bf2f(h2));
      Whi[d0 + 3][l] = h3; Wlo[d0 + 3][l] = f2bf(wv.w - bf2f(h3));
    }
  }
  bh8 aq[2][2];   // [m-tile][k-step]
  {
    const unsigned short* qbase = (const unsigned short*)qb + ((size_t)bh * Nn + (size_t)ch * 128) * Dn;
    #pragma unroll
    for (int m = 0; m < 2; ++m)
      #pragma unroll
      for (int ks = 0; ks < 2; ++ks)
        aq[m][ks] = *(const bh8*)(qbase + (size_t)(w * 32 + m * 16 + (lane & 15)) * Dn + ks * 32 + (lane >> 4) * 8);
  }
  __syncthreads();
  f4ev sacc[2][4];
  f4ev zz = {0.f, 0.f, 0.f, 0.f};
  #pragma unroll
  for (int m = 0; m < 2; ++m)
    #pragma unroll
    for (int nt = 0; nt < 4; ++nt) sacc[m][nt] = zz;
  #pragma unroll
  for (int ks = 0; ks < 2; ++ks)
    #pragma unroll
    for (int nt = 0; nt < 4; ++nt) {
      bh8 bhi = *(const bh8*)&Klhi[nt * 16 + (lane & 15)][ks * 32 + (lane >> 4) * 8];
      bh8 blo = *(const bh8*)&Kllo[nt * 16 + (lane & 15)][ks * 32 + (lane >> 4) * 8];
      #pragma unroll
      for (int m = 0; m < 2; ++m) {
        sacc[m][nt] = __builtin_amdgcn_mfma_f32_16x16x32_bf16(aq[m][ks], bhi, sacc[m][nt], 0, 0, 0);
        sacc[m][nt] = __builtin_amdgcn_mfma_f32_16x16x32_bf16(aq[m][ks], blo, sacc[m][nt], 0, 0, 0);
      }
    }
  float Pn[2][4][4];
  #pragma unroll
  for (int m = 0; m < 2; ++m)
    #pragma unroll
    for (int j = 0; j < 4; ++j) {
      float mx = sacc[m][0][j];
      #pragma unroll
      for (int nt = 1; nt < 4; ++nt) mx = fmaxf(mx, sacc[m][nt][j]);
      mx = fmaxf(mx, __shfl_xor(mx, 1));
      mx = fmaxf(mx, __shfl_xor(mx, 2));
      mx = fmaxf(mx, __shfl_xor(mx, 4));
      mx = fmaxf(mx, __shfl_xor(mx, 8));
      float sum = 0.f;
      #pragma unroll
      for (int nt = 0; nt < 4; ++nt) {
        float e = __expf(sacc[m][nt][j] - mx);
        Pn[m][nt][j] = e;
        sum += e;
      }
      sum += __shfl_xor(sum, 1);
      sum += __shfl_xor(sum, 2);
      sum += __shfl_xor(sum, 4);
      sum += __shfl_xor(sum, 8);
      float inv = 1.f / sum;
      #pragma unroll
      for (int nt = 0; nt < 4; ++nt) Pn[m][nt][j] *= inv;
    }
  __syncthreads();
  #pragma unroll
  for (int m = 0; m < 2; ++m)
    #pragma unroll
    for (int nt = 0; nt < 4; ++nt)
      #pragma unroll
      for (int j = 0; j < 4; ++j)
        Pl[w * 32 + m * 16 + (lane >> 4) * 4 + j][nt * 16 + (lane & 15)] = f2bf(Pn[m][nt][j]);
  __syncthreads();
  f4ev oacc[2][4];
  #pragma unroll
  for (int m = 0; m < 2; ++m)
    #pragma unroll
    for (int nt = 0; nt < 4; ++nt) oacc[m][nt] = zz;
  #pragma unroll
  for (int ks = 0; ks < 2; ++ks) {
    bh8 ap[2];
    #pragma unroll
    for (int m = 0; m < 2; ++m)
      ap[m] = *(const bh8*)&Pl[w * 32 + m * 16 + (lane & 15)][ks * 32 + (lane >> 4) * 8];
    #pragma unroll
    for (int nt = 0; nt < 4; ++nt) {
      bh8 bhi = *(const bh8*)&Whi[nt * 16 + (lane & 15)][ks * 32 + (lane >> 4) * 8];
      bh8 blo = *(const bh8*)&Wlo[nt * 16 + (lane & 15)][ks * 32 + (lane >> 4) * 8];
      #pragma unroll
      for (int m = 0; m < 2; ++m) {
        oacc[m][nt] = __builtin_amdgcn_mfma_f32_16x16x32_bf16(ap[m], bhi, oacc[m][nt], 0, 0, 0);
        oacc[m][nt] = __builtin_amdgcn_mfma_f32_16x16x32_bf16(ap[m], blo, oacc[m][nt], 0, 0, 0);
      }
    }
  }
  unsigned short* ohb = (unsigned short*)oh;
  #pragma unroll
  for (int m = 0; m < 2; ++m)
    #pragma unroll
    for (int nt = 0; nt < 4; ++nt)
      #pragma unroll
      for (int j = 0; j < 4; ++j) {
        int tok = ch * 128 + w * 32 + m * 16 + (lane >> 4) * 4 + j;
        int dd = nt * 16 + (lane & 15);
        ohb[((size_t)(b * Nn + tok)) * Cn + h * Dn + dd] = f2bf(oacc[m][nt][j]);
      }
}

// ---------- final projection: BK=32 swizzled, single-buffer (R13-proven) ----------
__launch_bounds__(256)
__global__ void gemm_proj_k(const __hip_bfloat16* __restrict__ A, const __hip_bfloat16* __restrict__ W,
                            const float* __restrict__ bias, float* __restrict__ out) {
  __shared__ unsigned short As[128][32], Bs[128][32];
  int t = threadIdx.x, lane = t & 63, w = t >> 6;
  int wr = w >> 1, wc = w & 1;
  int m0 = blockIdx.x * 128, n0 = blockIdx.y * 128;
  int srow = lane >> 2;
  int scol = (((lane & 3) ^ ((lane >> 3) & 3))) * 8;
  int rcol = (((lane >> 4) ^ ((lane >> 1) & 3))) * 8;
  f4ev acc[4][4];
  f4ev zz = {0.f, 0.f, 0.f, 0.f};
  #pragma unroll
  for (int m = 0; m < 4; ++m)
    #pragma unroll
    for (int n = 0; n < 4; ++n) acc[m][n] = zz;
  const __hip_bfloat16* ga = A + (size_t)(m0 + w * 16 + srow) * Cn + scol;
  const __hip_bfloat16* gb = W + (size_t)(n0 + w * 16 + srow) * Cn + scol;
  for (int k0 = 0; k0 < Cn; k0 += 32) {
    gload_lds16(ga + k0,                   &As[w * 16][0]);
    gload_lds16(ga + (size_t)64 * Cn + k0, &As[64 + w * 16][0]);
    gload_lds16(gb + k0,                   &Bs[w * 16][0]);
    gload_lds16(gb + (size_t)64 * Cn + k0, &Bs[64 + w * 16][0]);
    __syncthreads();
    bh8 af[4], bf_[4];
    #pragma unroll
    for (int m = 0; m < 4; ++m)
      af[m] = *(const bh8*)&As[wr * 64 + m * 16 + (lane & 15)][rcol];
    #pragma unroll
    for (int n = 0; n < 4; ++n)
      bf_[n] = *(const bh8*)&Bs[wc * 64 + n * 16 + (lane & 15)][rcol];
    #pragma unroll
    for (int m = 0; m < 4; ++m)
      #pragma unroll
      for (int n = 0; n < 4; ++n)
        acc[m][n] = __builtin_amdgcn_mfma_f32_16x16x32_bf16(af[m], bf_[n], acc[m][n], 0, 0, 0);
    __syncthreads();
  }
  #pragma unroll
  for (int m = 0; m < 4; ++m) {
    int rbase = m0 + wr * 64 + m * 16 + ((lane >> 4) << 2);
    #pragma unroll
    for (int n = 0; n < 4; ++n) {
      int c = n0 + wc * 64 + n * 16 + (lane & 15);
      float bv = bias[c];
      #pragma unroll
      for (int jj = 0; jj < 4; ++jj)
        out[(size_t)(rbase + jj) * Cn + c] = acc[m][n][jj] + bv;
    }
  }
}

extern "C" void kernel_launch(void* const* d_in, const int* in_sizes, int n_in,
                              void* d_out, int out_size, void* d_ws, size_t ws_size,
                              hipStream_t stream) {
  const float* x     = (const float*)d_in[0];
  const float* wqkv  = (const float*)d_in[1];
  const float* wproj = (const float*)d_in[2];
  const float* bproj = (const float*)d_in[3];
  float* out = (float*)d_out;
  char* ws = (char*)d_ws;

  auto xb   = (__hip_bfloat16*)(ws + OFF_XB);
  auto qb   = (__hip_bfloat16*)(ws + OFF_QB);
  auto kb   = (__hip_bfloat16*)(ws + OFF_KB);
  auto vb   = (__hip_bfloat16*)(ws + OFF_VB);
  auto wqb  = (__hip_bfloat16*)(ws + OFF_WQB);
  auto wpb  = (__hip_bfloat16*)(ws + OFF_WPB);
  auto ocp  = (float*)(ws + OFF_XB);            // alias: xb dead after gemm_qkv
  auto oh   = (__hip_bfloat16*)(ws + OFF_XB);   // alias: ocp dead after w2m
  auto part = (float*)(ws + OFF_QB);            // alias: qb not yet written
  auto xm   = (float*)(ws + OFF_XM);
  auto ql   = (float*)(ws + OFF_QL);
  auto kl   = (float*)(ws + OFF_KL);
  auto vinv = (float*)(ws + OFF_VINV);
  auto cp   = (float*)(ws + OFF_CP);
  auto w2   = (float*)(ws + OFF_W2);

  castmean_k<<<dim3(256, 2), 192, 0, stream>>>(x, (unsigned short*)xb, xm);
  castw_k<<<1536, 256, 0, stream>>>(wqkv, wproj, (unsigned short*)wqb, (unsigned short*)wpb);
  landgemm_k<<<dim3(4, 24, 12), 256, 0, stream>>>(xm, wqkv, part);
  landred_k<<<384, 256, 0, stream>>>(part, ql, kl);
  k2inv_k<<<48, 256, 0, stream>>>(ql, kl, vinv);
  gemm_qkv_k<<<dim3(128, 18), 256, 0, stream>>>(xb, wqb, qb, kb, vb);
  k3vflash_k<<<dim3(32, 48), 256, 0, stream>>>(ql, kb, vb, ocp, cp);
  k3vcomb_k<<<dim3(48, 16), 256, 0, stream>>>(ocp, cp);
  w2m_k<<<48, 256, 0, stream>>>(ocp, vinv, w2);
  k1app_k<<<dim3(32, 48), 256, 0, stream>>>(qb, kl, w2, oh);
  gemm_proj_k<<<dim3(128, 6), 256, 0, stream>>>(oh, wpb, bproj, out);
}

// Round 17
// 255.566 us; speedup vs baseline: 1.0614x; 1.0003x over previous
//
#include <hip/hip_runtime.h>
#include <hip/hip_bf16.h>

#define DI __device__ __forceinline__

typedef __attribute__((ext_vector_type(8))) short bh8;   // 8 bf16 (4 VGPR) MFMA frag
typedef __attribute__((ext_vector_type(8))) unsigned short us8;
typedef __attribute__((ext_vector_type(4))) float f4ev;  // MFMA f32 accumulator

static constexpr int Bn = 4;
static constexpr int Nn = 4096;
static constexpr int Cn = 768;
static constexpr int Hn = 12;
static constexpr int Dn = 64;    // head dim
static constexpr int Ln = 64;    // landmarks
static constexpr int TOKS = Bn * Nn;   // 16384
static constexpr int BHn = Bn * Hn;    // 48

// ---- workspace layout (bytes); stays within the proven ~110 MB footprint ----
static constexpr size_t SZ_XB  = (size_t)TOKS * Cn * 2;       // 25165824
static constexpr size_t SZ_QKV = (size_t)BHn * Nn * Dn * 2;   // 25165824
static constexpr size_t OFF_XB   = 0;                         // xb; later ocp; later oh
static constexpr size_t OFF_QB   = OFF_XB + SZ_XB;            // land partials live here pre-gemm_qkv
static constexpr size_t OFF_KB   = OFF_QB + SZ_QKV;
static constexpr size_t OFF_VB   = OFF_KB + SZ_QKV;
static constexpr size_t OFF_WQB  = OFF_VB + SZ_QKV;
static constexpr size_t OFF_WPB  = OFF_WQB + (size_t)3 * Cn * Cn * 2;
static constexpr size_t OFF_XM   = OFF_WPB + (size_t)Cn * Cn * 2;
static constexpr size_t OFF_QL   = OFF_XM + (size_t)Bn * Ln * Cn * 4;
static constexpr size_t OFF_KL   = OFF_QL + (size_t)Bn * Ln * Cn * 4;
static constexpr size_t OFF_VINV = OFF_KL + (size_t)Bn * Ln * Cn * 4;
static constexpr size_t OFF_CP   = OFF_VINV + (size_t)BHn * 64 * 64 * 4;  // stats: 48*32*64*2 f32
static constexpr size_t OFF_W2   = OFF_CP + (size_t)BHn * 32 * 64 * 2 * 4;

DI unsigned short f2bf(float f) {
  __hip_bfloat16 h = __float2bfloat16(f);
  return *reinterpret_cast<unsigned short*>(&h);
}
DI float bf2f(unsigned short u) {
  union { unsigned int i; float f; } c; c.i = ((unsigned)u) << 16; return c.f;
}

DI void gload_lds16(const void* g, void* l) {
  __builtin_amdgcn_global_load_lds((const __attribute__((address_space(1))) void*)g,
                                   (__attribute__((address_space(3))) void*)l, 16, 0, 0);
}

// ---------- cast both weight matrices (wqkv then wproj) in one launch ----------
__global__ void castw_k(const float* __restrict__ wqkv, const float* __restrict__ wproj,
                        unsigned short* __restrict__ dq, unsigned short* __restrict__ dp) {
  const int nq = 3 * Cn * Cn / 4;      // 442368 float4s
  const int np = Cn * Cn / 4;          // 147456 float4s
  int i = blockIdx.x * blockDim.x + threadIdx.x;
  int st = gridDim.x * blockDim.x;
  for (; i < nq + np; i += st) {
    const float4* s4;
    ushort4* d4;
    int idx;
    if (i < nq) { s4 = (const float4*)wqkv;  d4 = (ushort4*)dq; idx = i; }
    else        { s4 = (const float4*)wproj; d4 = (ushort4*)dp; idx = i - nq; }
    float4 v = s4[idx];
    ushort4 o; o.x = f2bf(v.x); o.y = f2bf(v.y); o.z = f2bf(v.z); o.w = f2bf(v.w);
    d4[idx] = o;
  }
}

// ---------- fused: cast x -> bf16 AND exact f32 segment-mean -> xm ----------
__global__ void castmean_k(const float* __restrict__ x, unsigned short* __restrict__ xb,
                           float* __restrict__ xm) {
  int bl = blockIdx.x, cz = blockIdx.y;
  int c = cz * 384 + threadIdx.x * 2;
  const float* xp = x + (size_t)bl * 64 * Cn + c;
  unsigned short* xbp = xb + (size_t)bl * 64 * Cn + c;
  float s0 = 0.f, s1 = 0.f;
  #pragma unroll 8
  for (int r = 0; r < 64; ++r) {
    float2 v = *(const float2*)(xp + (size_t)r * Cn);
    ushort2 o; o.x = f2bf(v.x); o.y = f2bf(v.y);
    *(ushort2*)(xbp + (size_t)r * Cn) = o;
    s0 += v.x; s1 += v.y;
  }
  xm[(size_t)bl * Cn + c]     = s0 * 0.015625f;
  xm[(size_t)bl * Cn + c + 1] = s1 * 0.015625f;
}

// ---------- landmark projection, K-split x12, register-blocked 4x4 ----------
__launch_bounds__(256)
__global__ void landgemm_k(const float* __restrict__ xm, const float* __restrict__ wqkv,
                           float* __restrict__ part) {
  __shared__ float XT[64][65];
  __shared__ float WT[64][65];
  int b = blockIdx.x, ct = blockIdx.y, kc = blockIdx.z;
  int t = threadIdx.x;
  int tr = t >> 4, tc = t & 15;
  int r0 = tr * 4, j0 = tc * 4;
  const float* xb_ = xm + (size_t)b * Ln * Cn + kc * 64;
  const float* wb_ = wqkv + (size_t)ct * 64 * Cn + kc * 64;
  #pragma unroll
  for (int i = t; i < 1024; i += 256) {
    int r = i >> 4, c4 = (i & 15) * 4;
    float4 xv = *(const float4*)(xb_ + (size_t)r * Cn + c4);
    XT[c4 + 0][r] = xv.x; XT[c4 + 1][r] = xv.y; XT[c4 + 2][r] = xv.z; XT[c4 + 3][r] = xv.w;
    float4 wv = *(const float4*)(wb_ + (size_t)r * Cn + c4);
    WT[c4 + 0][r] = wv.x; WT[c4 + 1][r] = wv.y; WT[c4 + 2][r] = wv.z; WT[c4 + 3][r] = wv.w;
  }
  __syncthreads();
  float acc[4][4];
  #pragma unroll
  for (int i = 0; i < 4; ++i)
    #pragma unroll
    for (int j = 0; j < 4; ++j) acc[i][j] = 0.f;
  for (int cc = 0; cc < 64; ++cc) {
    float4 a4 = *(const float4*)&XT[cc][r0];
    float4 b4 = *(const float4*)&WT[cc][j0];
    acc[0][0] += a4.x * b4.x; acc[0][1] += a4.x * b4.y; acc[0][2] += a4.x * b4.z; acc[0][3] += a4.x * b4.w;
    acc[1][0] += a4.y * b4.x; acc[1][1] += a4.y * b4.y; acc[1][2] += a4.y * b4.z; acc[1][3] += a4.y * b4.w;
    acc[2][0] += a4.z * b4.x; acc[2][1] += a4.z * b4.y; acc[2][2] += a4.z * b4.z; acc[2][3] += a4.z * b4.w;
    acc[3][0] += a4.w * b4.x; acc[3][1] += a4.w * b4.y; acc[3][2] += a4.w * b4.z; acc[3][3] += a4.w * b4.w;
  }
  float* op = part + ((size_t)kc * 256 + b * Ln) * 1536 + (size_t)ct * 64;
  #pragma unroll
  for (int i = 0; i < 4; ++i)
    *(float4*)(op + (size_t)(r0 + i) * 1536 + j0) = make_float4(acc[i][0], acc[i][1], acc[i][2], acc[i][3]);
}

// ---------- sum 12 K-split partials -> ql (x0.125), kl ----------
__global__ void landred_k(const float* __restrict__ part, float* __restrict__ ql,
                          float* __restrict__ kl) {
  int i4 = blockIdx.x * 256 + threadIdx.x;
  const float4* p4 = (const float4*)part;
  float4 s = p4[i4];
  #pragma unroll
  for (int kc = 1; kc < 12; ++kc) {
    float4 v = p4[(size_t)kc * 98304 + i4];
    s.x += v.x; s.y += v.y; s.z += v.z; s.w += v.w;
  }
  int row = i4 / 384, c = (i4 % 384) * 4;
  if (c < 768) {
    s.x *= 0.125f; s.y *= 0.125f; s.z *= 0.125f; s.w *= 0.125f;
    *(float4*)(ql + (size_t)row * Cn + c) = s;
  } else {
    *(float4*)(kl + (size_t)row * Cn + (c - 768)) = s;
  }
}

// ---------- kernel_2 softmax + 6-iter Newton-Schulz inverse ----------
__launch_bounds__(256)
__global__ void k2inv_k(const float* __restrict__ ql, const float* __restrict__ kl,
                        float* __restrict__ vinv) {
  __shared__ float B0[64][68], B1[64][68], B2[64][68], B3[64][68],
                   B4[64][68], B5[64][68], B6[64][68], B7[64][68];
  __shared__ float dinv_s;
  float (*Qt)[68] = B0, (*Kt)[68] = B1;
  float (*KV)[68] = B0, (*KVt)[68] = B1;
  float (*K2)[68] = B2, (*K2t)[68] = B3;
  float (*Vv)[68] = B4, (*Vt)[68] = B5;
  float (*T1)[68] = B6, (*Uu)[68] = B7;

  int bh = blockIdx.x, b = bh / Hn, h = bh % Hn;
  int t = threadIdx.x;
  int tr = t >> 4, tc = t & 15;
  int r0 = tr * 4, j0 = tc * 4;

  {
    const float* qbase = ql + (size_t)(b * Ln) * Cn + h * Dn;
    const float* kbase = kl + (size_t)(b * Ln) * Cn + h * Dn;
    #pragma unroll
    for (int it = 0; it < 4; ++it) {
      int idx = it * 256 + t;
      int l = idx >> 4, d0 = (idx & 15) * 4;
      float4 qv = *(const float4*)(qbase + (size_t)l * Cn + d0);
      float4 kv = *(const float4*)(kbase + (size_t)l * Cn + d0);
      Qt[d0 + 0][l] = qv.x; Qt[d0 + 1][l] = qv.y; Qt[d0 + 2][l] = qv.z; Qt[d0 + 3][l] = qv.w;
      Kt[d0 + 0][l] = kv.x; Kt[d0 + 1][l] = kv.y; Kt[d0 + 2][l] = kv.z; Kt[d0 + 3][l] = kv.w;
    }
  }
  __syncthreads();

  float acc[4][4];
  #define MM64(LT, RR)                                                     \
    {                                                                      \
      _Pragma("unroll")                                                    \
      for (int i_ = 0; i_ < 4; ++i_)                                       \
        _Pragma("unroll")                                                  \
        for (int j_ = 0; j_ < 4; ++j_) acc[i_][j_] = 0.f;                  \
      for (int c_ = 0; c_ < 64; c_ += 4) {                                 \
        _Pragma("unroll")                                                  \
        for (int cc_ = 0; cc_ < 4; ++cc_) {                                \
          float4 a4 = *(const float4*)&LT[c_ + cc_][r0];                   \
          float4 b4 = *(const float4*)&RR[c_ + cc_][j0];                   \
          acc[0][0] += a4.x * b4.x; acc[0][1] += a4.x * b4.y;              \
          acc[0][2] += a4.x * b4.z; acc[0][3] += a4.x * b4.w;              \
          acc[1][0] += a4.y * b4.x; acc[1][1] += a4.y * b4.y;              \
          acc[1][2] += a4.y * b4.z; acc[1][3] += a4.y * b4.w;              \
          acc[2][0] += a4.z * b4.x; acc[2][1] += a4.z * b4.y;              \
          acc[2][2] += a4.z * b4.z; acc[2][3] += a4.z * b4.w;              \
          acc[3][0] += a4.w * b4.x; acc[3][1] += a4.w * b4.y;              \
          acc[3][2] += a4.w * b4.z; acc[3][3] += a4.w * b4.w;              \
        }                                                                  \
      }                                                                    \
    }

  MM64(Qt, Kt);
  #pragma unroll
  for (int i = 0; i < 4; ++i)
    *(float4*)&K2[r0 + i][j0] = make_float4(acc[i][0], acc[i][1], acc[i][2], acc[i][3]);
  __syncthreads();

  if (t < 64) {
    float m = -1e30f;
    #pragma unroll
    for (int c4 = 0; c4 < 16; ++c4) {
      float4 v = *(const float4*)&K2[t][c4 * 4];
      m = fmaxf(m, fmaxf(fmaxf(v.x, v.y), fmaxf(v.z, v.w)));
    }
    float s = 0.f;
    #pragma unroll
    for (int c4 = 0; c4 < 16; ++c4) {
      float4 v = *(const float4*)&K2[t][c4 * 4];
      v.x = __expf(v.x - m); v.y = __expf(v.y - m);
      v.z = __expf(v.z - m); v.w = __expf(v.w - m);
      s += v.x + v.y + v.z + v.w;
      *(float4*)&K2[t][c4 * 4] = v;
    }
    float inv = 1.f / s;
    #pragma unroll
    for (int c4 = 0; c4 < 16; ++c4) {
      float4 v = *(const float4*)&K2[t][c4 * 4];
      v.x *= inv; v.y *= inv; v.z *= inv; v.w *= inv;
      *(float4*)&K2[t][c4 * 4] = v;
      K2t[c4 * 4 + 0][t] = v.x; K2t[c4 * 4 + 1][t] = v.y;
      K2t[c4 * 4 + 2][t] = v.z; K2t[c4 * 4 + 3][t] = v.w;
    }
  }
  __syncthreads();
  if (t < 64) {
    float cs = 0.f;
    #pragma unroll
    for (int c4 = 0; c4 < 16; ++c4) {
      float4 v = *(const float4*)&K2t[t][c4 * 4];
      cs += v.x + v.y + v.z + v.w;
    }
    #pragma unroll
    for (int off = 1; off < 64; off <<= 1) cs = fmaxf(cs, __shfl_xor(cs, off));
    if (t == 0) dinv_s = 1.f / cs;
  }
  __syncthreads();
  float dinv = dinv_s;
  #pragma unroll
  for (int jj = 0; jj < 4; ++jj) {
    float4 k4 = *(const float4*)&K2[j0 + jj][r0];
    k4.x *= dinv; k4.y *= dinv; k4.z *= dinv; k4.w *= dinv;
    *(float4*)&Vt[j0 + jj][r0] = k4;
    Vv[r0 + 0][j0 + jj] = k4.x; Vv[r0 + 1][j0 + jj] = k4.y;
    Vv[r0 + 2][j0 + jj] = k4.z; Vv[r0 + 3][j0 + jj] = k4.w;
  }
  __syncthreads();

  float nv[4][4];
  for (int itn = 0; itn < 6; ++itn) {
    MM64(K2t, Vv);
    #pragma unroll
    for (int i = 0; i < 4; ++i)
      *(float4*)&KV[r0 + i][j0] = make_float4(acc[i][0], acc[i][1], acc[i][2], acc[i][3]);
    #pragma unroll
    for (int jj = 0; jj < 4; ++jj)
      *(float4*)&KVt[j0 + jj][r0] = make_float4(acc[0][jj], acc[1][jj], acc[2][jj], acc[3][jj]);
    __syncthreads();
    MM64(KVt, KV);
    #pragma unroll
    for (int i = 0; i < 4; ++i) {
      float4 kv4 = *(const float4*)&KV[r0 + i][j0];
      *(float4*)&T1[r0 + i][j0] = make_float4(7.f * kv4.x - acc[i][0], 7.f * kv4.y - acc[i][1],
                                              7.f * kv4.z - acc[i][2], 7.f * kv4.w - acc[i][3]);
    }
    __syncthreads();
    MM64(KVt, T1);
    #pragma unroll
    for (int i = 0; i < 4; ++i) {
      float4 kv4 = *(const float4*)&KV[r0 + i][j0];
      *(float4*)&Uu[r0 + i][j0] = make_float4(15.f * kv4.x - acc[i][0], 15.f * kv4.y - acc[i][1],
                                              15.f * kv4.z - acc[i][2], 15.f * kv4.w - acc[i][3]);
    }
    __syncthreads();
    MM64(Vt, Uu);
    #pragma unroll
    for (int i = 0; i < 4; ++i) {
      float4 v4 = *(const float4*)&Vv[r0 + i][j0];
      nv[i][0] = 0.25f * (13.f * v4.x - acc[i][0]);
      nv[i][1] = 0.25f * (13.f * v4.y - acc[i][1]);
      nv[i][2] = 0.25f * (13.f * v4.z - acc[i][2]);
      nv[i][3] = 0.25f * (13.f * v4.w - acc[i][3]);
    }
    __syncthreads();
    #pragma unroll
    for (int i = 0; i < 4; ++i)
      *(float4*)&Vv[r0 + i][j0] = make_float4(nv[i][0], nv[i][1], nv[i][2], nv[i][3]);
    #pragma unroll
    for (int jj = 0; jj < 4; ++jj)
      *(float4*)&Vt[j0 + jj][r0] = make_float4(nv[0][jj], nv[1][jj], nv[2][jj], nv[3][jj]);
    __syncthreads();
  }
  float* op = vinv + (size_t)bh * 4096;
  #pragma unroll
  for (int i = 0; i < 4; ++i)
    *(float4*)(op + (size_t)(r0 + i) * 64 + j0) = make_float4(nv[i][0], nv[i][1], nv[i][2], nv[i][3]);
  #undef MM64
}

// ---------- big GEMM: BK=64 dbuf + counted-vmcnt 2-phase (T4 refinement) ----------
// Per K-tile: issue STAGE(next) -> vmcnt(8) [prev tile landed, new 8 in flight]
// -> barrier [globalizes] -> ds_read+MFMA(cur) -> lgkmcnt(0)+barrier [reads done].
// No vmcnt(0) in steady state: prefetch spans a full extra compute phase.
__launch_bounds__(256)
__global__ void gemm_qkv_k(const __hip_bfloat16* __restrict__ A, const __hip_bfloat16* __restrict__ W,
                           __hip_bfloat16* __restrict__ qb, __hip_bfloat16* __restrict__ kb,
                           __hip_bfloat16* __restrict__ vb) {
  __shared__ unsigned short As[2][128][64], Bs[2][128][64];   // 64 KB
  int t = threadIdx.x, lane = t & 63, w = t >> 6;
  int wr = w >> 1, wc = w & 1;
  int m0 = blockIdx.x * 128, n0 = blockIdx.y * 128;
  int srow = w * 8 + (lane >> 3);
  int scol = ((lane & 7) ^ ((lane >> 3) & 7)) * 8;       // pre-swizzled source col
  f4ev acc[4][4];
  f4ev zz = {0.f, 0.f, 0.f, 0.f};
  #pragma unroll
  for (int m = 0; m < 4; ++m)
    #pragma unroll
    for (int n = 0; n < 4; ++n) acc[m][n] = zz;
  const __hip_bfloat16* ga = A + (size_t)(m0 + srow) * Cn + scol;
  const __hip_bfloat16* gb = W + (size_t)(n0 + srow) * Cn + scol;

  // prologue: stage K-tile 0 into buffer 0, full drain
  #pragma unroll
  for (int c = 0; c < 4; ++c) {
    gload_lds16(ga + (size_t)(c * 32) * Cn, &As[0][c * 32 + w * 8][0]);
    gload_lds16(gb + (size_t)(c * 32) * Cn, &Bs[0][c * 32 + w * 8][0]);
  }
  asm volatile("s_waitcnt vmcnt(0)" ::: "memory");
  __builtin_amdgcn_s_barrier();
  int cur = 0;
  for (int it = 0; it < 12; ++it) {
    if (it < 11) {
      int k0 = (it + 1) * 64;
      #pragma unroll
      for (int c = 0; c < 4; ++c) {
        gload_lds16(ga + (size_t)(c * 32) * Cn + k0, &As[cur ^ 1][c * 32 + w * 8][0]);
        gload_lds16(gb + (size_t)(c * 32) * Cn + k0, &Bs[cur ^ 1][c * 32 + w * 8][0]);
      }
      // wait only for the PREVIOUS tile's 8 loads (this iter's 8 stay in flight)
      asm volatile("s_waitcnt vmcnt(8)" ::: "memory");
    } else {
      asm volatile("s_waitcnt vmcnt(0)" ::: "memory");   // last tile: drain fully
    }
    __builtin_amdgcn_s_barrier();   // tile `cur` ready across all waves
    #pragma unroll
    for (int ks = 0; ks < 2; ++ks) {
      int pc = ((ks * 4 + (lane >> 4)) ^ (lane & 7)) * 8;  // swizzled read col
      bh8 af[4], bf_[4];
      #pragma unroll
      for (int m = 0; m < 4; ++m)
        af[m] = *(const bh8*)&As[cur][wr * 64 + m * 16 + (lane & 15)][pc];
      #pragma unroll
      for (int n = 0; n < 4; ++n)
        bf_[n] = *(const bh8*)&Bs[cur][wc * 64 + n * 16 + (lane & 15)][pc];
      #pragma unroll
      for (int m = 0; m < 4; ++m)
        #pragma unroll
        for (int n = 0; n < 4; ++n)
          acc[m][n] = __builtin_amdgcn_mfma_f32_16x16x32_bf16(af[m], bf_[n], acc[m][n], 0, 0, 0);
    }
    asm volatile("s_waitcnt lgkmcnt(0)" ::: "memory");
    __builtin_amdgcn_s_barrier();   // all reads of buf[cur] done -> safe to overwrite
    cur ^= 1;
  }
  int which = (n0 >= 1536) ? 2 : (n0 >= 768 ? 1 : 0);
  __hip_bfloat16* dst = which == 0 ? qb : (which == 1 ? kb : vb);
  float sc = which == 0 ? 0.125f : 1.f;
  #pragma unroll
  for (int m = 0; m < 4; ++m) {
    int rbase = m0 + wr * 64 + m * 16 + ((lane >> 4) << 2);
    #pragma unroll
    for (int n = 0; n < 4; ++n) {
      int c = n0 + wc * 64 + n * 16 + (lane & 15);
      int rem = c - which * 768;
      int h = rem >> 6, dd = rem & 63;
      #pragma unroll
      for (int jj = 0; jj < 4; ++jj) {
        int r = rbase + jj;
        int b = r >> 12, ntok = r & 4095;
        dst[(((size_t)(b * Hn + h) * Nn + ntok) << 6) + dd] = __float2bfloat16(acc[m][n][jj] * sc);
      }
    }
  }
}

// ---------- fused flash-style kernel_3 softmax + @v over 128-token chunks ----------
__launch_bounds__(256)
__global__ void k3vflash_k(const float* __restrict__ ql, const __hip_bfloat16* __restrict__ kb,
                           const __hip_bfloat16* __restrict__ vb,
                           float* __restrict__ ocp, float* __restrict__ stat) {
  __shared__ unsigned short Ks[128][72];   // K tile [token][d]; reused as Pl[64][136]
  __shared__ unsigned short VT[64][136];   // V^T tile [d][token]
  auto Pl = (unsigned short (*)[136]) & Ks[0][0];
  int ch = blockIdx.x, bh = blockIdx.y;
  int b = bh / Hn, h = bh % Hn;
  int t = threadIdx.x, lane = t & 63, w = t >> 6;

  {
    int row = t >> 1, half = (t & 1) * 32;
    const us8* krow = (const us8*)((const unsigned short*)kb + ((size_t)bh * Nn + (size_t)ch * 128 + row) * Dn + half);
    const us8* vrow = (const us8*)((const unsigned short*)vb + ((size_t)bh * Nn + (size_t)ch * 128 + row) * Dn + half);
    us8 kv0 = krow[0], kv1 = krow[1], kv2 = krow[2], kv3 = krow[3];
    us8 vv0 = vrow[0], vv1 = vrow[1], vv2 = vrow[2], vv3 = vrow[3];
    *(us8*)&Ks[row][half + 0]  = kv0;
    *(us8*)&Ks[row][half + 8]  = kv1;
    *(us8*)&Ks[row][half + 16] = kv2;
    *(us8*)&Ks[row][half + 24] = kv3;
    #pragma unroll
    for (int e = 0; e < 8; ++e) {
      VT[half + e][row]      = vv0[e];
      VT[half + 8 + e][row]  = vv1[e];
      VT[half + 16 + e][row] = vv2[e];
      VT[half + 24 + e][row] = vv3[e];
    }
  }
  bh8 aq[2];
  {
    const float* qrow = ql + ((size_t)(b * Ln + w * 16 + (lane & 15))) * Cn + h * Dn + (lane >> 4) * 8;
    #pragma unroll
    for (int ks = 0; ks < 2; ++ks) {
      float4 f0 = *(const float4*)(qrow + ks * 32);
      float4 f1 = *(const float4*)(qrow + ks * 32 + 4);
      bh8 v;
      v[0] = (short)f2bf(f0.x); v[1] = (short)f2bf(f0.y); v[2] = (short)f2bf(f0.z); v[3] = (short)f2bf(f0.w);
      v[4] = (short)f2bf(f1.x); v[5] = (short)f2bf(f1.y); v[6] = (short)f2bf(f1.z); v[7] = (short)f2bf(f1.w);
      aq[ks] = v;
    }
  }
  __syncthreads();
  f4ev sacc[8];
  f4ev zz = {0.f, 0.f, 0.f, 0.f};
  #pragma unroll
  for (int nt = 0; nt < 8; ++nt) sacc[nt] = zz;
  #pragma unroll
  for (int ks = 0; ks < 2; ++ks)
    #pragma unroll
    for (int nt = 0; nt < 8; ++nt) {
      bh8 bk = *(const bh8*)&Ks[nt * 16 + (lane & 15)][ks * 32 + (lane >> 4) * 8];
      sacc[nt] = __builtin_amdgcn_mfma_f32_16x16x32_bf16(aq[ks], bk, sacc[nt], 0, 0, 0);
    }
  float M[4];
  #pragma unroll
  for (int j = 0; j < 4; ++j) {
    float m = sacc[0][j];
    #pragma unroll
    for (int nt = 1; nt < 8; ++nt) m = fmaxf(m, sacc[nt][j]);
    m = fmaxf(m, __shfl_xor(m, 1));
    m = fmaxf(m, __shfl_xor(m, 2));
    m = fmaxf(m, __shfl_xor(m, 4));
    m = fmaxf(m, __shfl_xor(m, 8));
    M[j] = m;
  }
  __syncthreads();
  float Ssum[4] = {0.f, 0.f, 0.f, 0.f};
  #pragma unroll
  for (int nt = 0; nt < 8; ++nt)
    #pragma unroll
    for (int j = 0; j < 4; ++j) {
      float pf = __expf(sacc[nt][j] - M[j]);
      Ssum[j] += pf;
      Pl[w * 16 + (lane >> 4) * 4 + j][nt * 16 + (lane & 15)] = f2bf(pf);
    }
  #pragma unroll
  for (int j = 0; j < 4; ++j) {
    float s = Ssum[j];
    s += __shfl_xor(s, 1);
    s += __shfl_xor(s, 2);
    s += __shfl_xor(s, 4);
    s += __shfl_xor(s, 8);
    Ssum[j] = s;
  }
  if ((lane & 15) == 0) {
    #pragma unroll
    for (int j = 0; j < 4; ++j) {
      int l2 = w * 16 + (lane >> 4) * 4 + j;
      float* sp = stat + (((size_t)bh * 32 + ch) * 64 + l2) * 2;
      sp[0] = M[j]; sp[1] = Ssum[j];
    }
  }
  __syncthreads();
  f4ev oacc[4];
  #pragma unroll
  for (int nt = 0; nt < 4; ++nt) oacc[nt] = zz;
  #pragma unroll
  for (int ks = 0; ks < 4; ++ks) {
    bh8 ap = *(const bh8*)&Pl[w * 16 + (lane & 15)][ks * 32 + (lane >> 4) * 8];
    #pragma unroll
    for (int nt = 0; nt < 4; ++nt) {
      bh8 bv = *(const bh8*)&VT[nt * 16 + (lane & 15)][ks * 32 + (lane >> 4) * 8];
      oacc[nt] = __builtin_amdgcn_mfma_f32_16x16x32_bf16(ap, bv, oacc[nt], 0, 0, 0);
    }
  }
  float* ob = ocp + (((size_t)bh * 32 + ch) * 64) * 64;
  #pragma unroll
  for (int nt = 0; nt < 4; ++nt)
    #pragma unroll
    for (int j = 0; j < 4; ++j) {
      int l2 = w * 16 + ((lane >> 4) << 2) + j;
      ob[l2 * 64 + nt * 16 + (lane & 15)] = oacc[nt][j];
    }
}

// ---------- wide combine: 32 chunk partials -> normalized k3v (in chunk-0 slot) ----
__global__ void k3vcomb_k(float* __restrict__ ocp, const float* __restrict__ stat) {
  int bh = blockIdx.x, rg = blockIdx.y;
  int t = threadIdx.x;
  int row = rg * 4 + (t >> 6), col = t & 63;
  const float* sp = stat + (size_t)bh * 32 * 128 + row * 2;
  float M = -1e30f;
  #pragma unroll
  for (int c = 0; c < 32; ++c) M = fmaxf(M, sp[c * 128]);
  float S = 0.f;
  float wcb[32];
  #pragma unroll
  for (int c = 0; c < 32; ++c) {
    float wv = __expf(sp[c * 128] - M);
    wcb[c] = wv;
    S += wv * sp[c * 128 + 1];
  }
  float inv = 1.f / S;
  float* base = ocp + (size_t)bh * 32 * 4096 + row * 64 + col;
  float acc = 0.f;
  #pragma unroll
  for (int c = 0; c < 32; ++c) acc += base[(size_t)c * 4096] * wcb[c];
  *base = acc * inv;   // chunk-0 slot; this block exclusively owns these rows
}

// ---------- small matmul: W2 = Vinv @ k3v ----------
__global__ void w2m_k(const float* __restrict__ ocp, const float* __restrict__ vinv,
                      float* __restrict__ w2) {
  __shared__ float kv[64][72], vi[64][72];
  int bh = blockIdx.x, t = threadIdx.x, j = t & 63, ig = t >> 6;
  for (int i = t; i < 4096; i += 256) {
    kv[i >> 6][i & 63] = ocp[(size_t)bh * 32 * 4096 + i];
    vi[i >> 6][i & 63] = vinv[(size_t)bh * 4096 + i];
  }
  __syncthreads();
  float a[16];
  #pragma unroll
  for (int li = 0; li < 16; ++li) a[li] = 0.f;
  for (int c2 = 0; c2 < 64; ++c2) {
    float vv = kv[c2][j];
    #pragma unroll
    for (int li = 0; li < 16; ++li) a[li] += vi[ig * 16 + li][c2] * vv;
  }
  #pragma unroll
  for (int li = 0; li < 16; ++li) w2[(size_t)bh * 4096 + (ig * 16 + li) * 64 + j] = a[li];
}

// ---------- kernel_1 apply via MFMA: oh = softmax(q@kl^T) @ W2 ----------
__launch_bounds__(256)
__global__ void k1app_k(const __hip_bfloat16* __restrict__ qb, const float* __restrict__ kl,
                        const float* __restrict__ w2, __hip_bfloat16* __restrict__ oh) {
  __shared__ unsigned short SM[128 * 72 + 64 * 72 * 2];  // 36864 B
  auto Klhi = (unsigned short (*)[72])(SM);              // [64][72]
  auto Kllo = (unsigned short (*)[72])(SM + 64 * 72);    // [64][72]
  auto Pl   = (unsigned short (*)[72])(SM);              // [128][72], aliases Klhi+Kllo
  auto Whi  = (unsigned short (*)[72])(SM + 128 * 72);           // W2T hi [d][lm]
  auto Wlo  = (unsigned short (*)[72])(SM + 128 * 72 + 64 * 72); // W2T lo [d][lm]

  int ch = blockIdx.x, bh = blockIdx.y;
  int b = bh / Hn, h = bh % Hn;
  int t = threadIdx.x, lane = t & 63, w = t >> 6;

  {
    const float* klb = kl + (size_t)(b * Ln) * Cn + h * Dn;
    const float* w2b = w2 + (size_t)bh * 4096;
    #pragma unroll
    for (int it = 0; it < 4; ++it) {
      int idx = it * 256 + t;
      int l = idx >> 4, d0 = (idx & 15) * 4;
      float4 kv = *(const float4*)(klb + (size_t)l * Cn + d0);
      ushort4 hi4; ushort4 lo4;
      hi4.x = f2bf(kv.x); lo4.x = f2bf(kv.x - bf2f(hi4.x));
      hi4.y = f2bf(kv.y); lo4.y = f2bf(kv.y - bf2f(hi4.y));
      hi4.z = f2bf(kv.z); lo4.z = f2bf(kv.z - bf2f(hi4.z));
      hi4.w = f2bf(kv.w); lo4.w = f2bf(kv.w - bf2f(hi4.w));
      *(ushort4*)&Klhi[l][d0] = hi4;
      *(ushort4*)&Kllo[l][d0] = lo4;
      float4 wv = *(const float4*)(w2b + (size_t)l * 64 + d0);
      unsigned short h0 = f2bf(wv.x), h1 = f2bf(wv.y), h2 = f2bf(wv.z), h3 = f2bf(wv.w);
      Whi[d0 + 0][l] = h0; Wlo[d0 + 0][l] = f2bf(wv.x - bf2f(h0));
      Whi[d0 + 1][l] = h1; Wlo[d0 + 1][l] = f2bf(wv.y - bf2f(h1));
      Whi[d0 + 2][l] = h2; Wlo[d0 + 2][l] = f2bf(wv.z - bf2f(h2));
      Whi[d0 + 3][l] = h3; Wlo[d0 + 3][l] = f2bf(wv.w - bf2f(h3));
    }
  }
  bh8 aq[2][2];   // [m-tile][k-step]
  {
    const unsigned short* qbase = (const unsigned short*)qb + ((size_t)bh * Nn + (size_t)ch * 128) * Dn;
    #pragma unroll
    for (int m = 0; m < 2; ++m)
      #pragma unroll
      for (int ks = 0; ks < 2; ++ks)
        aq[m][ks] = *(const bh8*)(qbase + (size_t)(w * 32 + m * 16 + (lane & 15)) * Dn + ks * 32 + (lane >> 4) * 8);
  }
  __syncthreads();
  f4ev sacc[2][4];
  f4ev zz = {0.f, 0.f, 0.f, 0.f};
  #pragma unroll
  for (int m = 0; m < 2; ++m)
    #pragma unroll
    for (int nt = 0; nt < 4; ++nt) sacc[m][nt] = zz;
  #pragma unroll
  for (int ks = 0; ks < 2; ++ks)
    #pragma unroll
    for (int nt = 0; nt < 4; ++nt) {
      bh8 bhi = *(const bh8*)&Klhi[nt * 16 + (lane & 15)][ks * 32 + (lane >> 4) * 8];
      bh8 blo = *(const bh8*)&Kllo[nt * 16 + (lane & 15)][ks * 32 + (lane >> 4) * 8];
      #pragma unroll
      for (int m = 0; m < 2; ++m) {
        sacc[m][nt] = __builtin_amdgcn_mfma_f32_16x16x32_bf16(aq[m][ks], bhi, sacc[m][nt], 0, 0, 0);
        sacc[m][nt] = __builtin_amdgcn_mfma_f32_16x16x32_bf16(aq[m][ks], blo, sacc[m][nt], 0, 0, 0);
      }
    }
  float Pn[2][4][4];
  #pragma unroll
  for (int m = 0; m < 2; ++m)
    #pragma unroll
    for (int j = 0; j < 4; ++j) {
      float mx = sacc[m][0][j];
      #pragma unroll
      for (int nt = 1; nt < 4; ++nt) mx = fmaxf(mx, sacc[m][nt][j]);
      mx = fmaxf(mx, __shfl_xor(mx, 1));
      mx = fmaxf(mx, __shfl_xor(mx, 2));
      mx = fmaxf(mx, __shfl_xor(mx, 4));
      mx = fmaxf(mx, __shfl_xor(mx, 8));
      float sum = 0.f;
      #pragma unroll
      for (int nt = 0; nt < 4; ++nt) {
        float e = __expf(sacc[m][nt][j] - mx);
        Pn[m][nt][j] = e;
        sum += e;
      }
      sum += __shfl_xor(sum, 1);
      sum += __shfl_xor(sum, 2);
      sum += __shfl_xor(sum, 4);
      sum += __shfl_xor(sum, 8);
      float inv = 1.f / sum;
      #pragma unroll
      for (int nt = 0; nt < 4; ++nt) Pn[m][nt][j] *= inv;
    }
  __syncthreads();
  #pragma unroll
  for (int m = 0; m < 2; ++m)
    #pragma unroll
    for (int nt = 0; nt < 4; ++nt)
      #pragma unroll
      for (int j = 0; j < 4; ++j)
        Pl[w * 32 + m * 16 + (lane >> 4) * 4 + j][nt * 16 + (lane & 15)] = f2bf(Pn[m][nt][j]);
  __syncthreads();
  f4ev oacc[2][4];
  #pragma unroll
  for (int m = 0; m < 2; ++m)
    #pragma unroll
    for (int nt = 0; nt < 4; ++nt) oacc[m][nt] = zz;
  #pragma unroll
  for (int ks = 0; ks < 2; ++ks) {
    bh8 ap[2];
    #pragma unroll
    for (int m = 0; m < 2; ++m)
      ap[m] = *(const bh8*)&Pl[w * 32 + m * 16 + (lane & 15)][ks * 32 + (lane >> 4) * 8];
    #pragma unroll
    for (int nt = 0; nt < 4; ++nt) {
      bh8 bhi = *(const bh8*)&Whi[nt * 16 + (lane & 15)][ks * 32 + (lane >> 4) * 8];
      bh8 blo = *(const bh8*)&Wlo[nt * 16 + (lane & 15)][ks * 32 + (lane >> 4) * 8];
      #pragma unroll
      for (int m = 0; m < 2; ++m) {
        oacc[m][nt] = __builtin_amdgcn_mfma_f32_16x16x32_bf16(ap[m], bhi, oacc[m][nt], 0, 0, 0);
        oacc[m][nt] = __builtin_amdgcn_mfma_f32_16x16x32_bf16(ap[m], blo, oacc[m][nt], 0, 0, 0);
      }
    }
  }
  unsigned short* ohb = (unsigned short*)oh;
  #pragma unroll
  for (int m = 0; m < 2; ++m)
    #pragma unroll
    for (int nt = 0; nt < 4; ++nt)
      #pragma unroll
      for (int j = 0; j < 4; ++j) {
        int tok = ch * 128 + w * 32 + m * 16 + (lane >> 4) * 4 + j;
        int dd = nt * 16 + (lane & 15);
        ohb[((size_t)(b * Nn + tok)) * Cn + h * Dn + dd] = f2bf(oacc[m][nt][j]);
      }
}

// ---------- final projection: BK=32 swizzled, single-buffer (R13-proven) ----------
__launch_bounds__(256)
__global__ void gemm_proj_k(const __hip_bfloat16* __restrict__ A, const __hip_bfloat16* __restrict__ W,
                            const float* __restrict__ bias, float* __restrict__ out) {
  __shared__ unsigned short As[128][32], Bs[128][32];
  int t = threadIdx.x, lane = t & 63, w = t >> 6;
  int wr = w >> 1, wc = w & 1;
  int m0 = blockIdx.x * 128, n0 = blockIdx.y * 128;
  int srow = lane >> 2;
  int scol = (((lane & 3) ^ ((lane >> 3) & 3))) * 8;
  int rcol = (((lane >> 4) ^ ((lane >> 1) & 3))) * 8;
  f4ev acc[4][4];
  f4ev zz = {0.f, 0.f, 0.f, 0.f};
  #pragma unroll
  for (int m = 0; m < 4; ++m)
    #pragma unroll
    for (int n = 0; n < 4; ++n) acc[m][n] = zz;
  const __hip_bfloat16* ga = A + (size_t)(m0 + w * 16 + srow) * Cn + scol;
  const __hip_bfloat16* gb = W + (size_t)(n0 + w * 16 + srow) * Cn + scol;
  for (int k0 = 0; k0 < Cn; k0 += 32) {
    gload_lds16(ga + k0,                   &As[w * 16][0]);
    gload_lds16(ga + (size_t)64 * Cn + k0, &As[64 + w * 16][0]);
    gload_lds16(gb + k0,                   &Bs[w * 16][0]);
    gload_lds16(gb + (size_t)64 * Cn + k0, &Bs[64 + w * 16][0]);
    __syncthreads();
    bh8 af[4], bf_[4];
    #pragma unroll
    for (int m = 0; m < 4; ++m)
      af[m] = *(const bh8*)&As[wr * 64 + m * 16 + (lane & 15)][rcol];
    #pragma unroll
    for (int n = 0; n < 4; ++n)
      bf_[n] = *(const bh8*)&Bs[wc * 64 + n * 16 + (lane & 15)][rcol];
    #pragma unroll
    for (int m = 0; m < 4; ++m)
      #pragma unroll
      for (int n = 0; n < 4; ++n)
        acc[m][n] = __builtin_amdgcn_mfma_f32_16x16x32_bf16(af[m], bf_[n], acc[m][n], 0, 0, 0);
    __syncthreads();
  }
  #pragma unroll
  for (int m = 0; m < 4; ++m) {
    int rbase = m0 + wr * 64 + m * 16 + ((lane >> 4) << 2);
    #pragma unroll
    for (int n = 0; n < 4; ++n) {
      int c = n0 + wc * 64 + n * 16 + (lane & 15);
      float bv = bias[c];
      #pragma unroll
      for (int jj = 0; jj < 4; ++jj)
        out[(size_t)(rbase + jj) * Cn + c] = acc[m][n][jj] + bv;
    }
  }
}

extern "C" void kernel_launch(void* const* d_in, const int* in_sizes, int n_in,
                              void* d_out, int out_size, void* d_ws, size_t ws_size,
                              hipStream_t stream) {
  const float* x     = (const float*)d_in[0];
  const float* wqkv  = (const float*)d_in[1];
  const float* wproj = (const float*)d_in[2];
  const float* bproj = (const float*)d_in[3];
  float* out = (float*)d_out;
  char* ws = (char*)d_ws;

  auto xb   = (__hip_bfloat16*)(ws + OFF_XB);
  auto qb   = (__hip_bfloat16*)(ws + OFF_QB);
  auto kb   = (__hip_bfloat16*)(ws + OFF_KB);
  auto vb   = (__hip_bfloat16*)(ws + OFF_VB);
  auto wqb  = (__hip_bfloat16*)(ws + OFF_WQB);
  auto wpb  = (__hip_bfloat16*)(ws + OFF_WPB);
  auto ocp  = (float*)(ws + OFF_XB);            // alias: xb dead after gemm_qkv
  auto oh   = (__hip_bfloat16*)(ws + OFF_XB);   // alias: ocp dead after w2m
  auto part = (float*)(ws + OFF_QB);            // alias: qb not yet written
  auto xm   = (float*)(ws + OFF_XM);
  auto ql   = (float*)(ws + OFF_QL);
  auto kl   = (float*)(ws + OFF_KL);
  auto vinv = (float*)(ws + OFF_VINV);
  auto cp   = (float*)(ws + OFF_CP);
  auto w2   = (float*)(ws + OFF_W2);

  castmean_k<<<dim3(256, 2), 192, 0, stream>>>(x, (unsigned short*)xb, xm);
  castw_k<<<1536, 256, 0, stream>>>(wqkv, wproj, (unsigned short*)wqb, (unsigned short*)wpb);
  landgemm_k<<<dim3(4, 24, 12), 256, 0, stream>>>(xm, wqkv, part);
  landred_k<<<384, 256, 0, stream>>>(part, ql, kl);
  k2inv_k<<<48, 256, 0, stream>>>(ql, kl, vinv);
  gemm_qkv_k<<<dim3(128, 18), 256, 0, stream>>>(xb, wqb, qb, kb, vb);
  k3vflash_k<<<dim3(32, 48), 256, 0, stream>>>(ql, kb, vb, ocp, cp);
  k3vcomb_k<<<dim3(48, 16), 256, 0, stream>>>(ocp, cp);
  w2m_k<<<48, 256, 0, stream>>>(ocp, vinv, w2);
  k1app_k<<<dim3(32, 48), 256, 0, stream>>>(qb, kl, w2, oh);
  gemm_proj_k<<<dim3(128, 6), 256, 0, stream>>>(oh, wpb, bproj, out);
}